// Round 14
// baseline (117.209 us; speedup 1.0000x reference)
//
#include <hip/hip_runtime.h>
#include <stdint.h>

#define S_LEN 2048
#define EMB   768
#define NHEAD 12
#define HDIM  64

typedef __attribute__((ext_vector_type(8)))  __bf16       bf16x8;
typedef __attribute__((ext_vector_type(4)))  float        f32x4;
typedef __attribute__((ext_vector_type(16))) float        f32x16;
typedef __attribute__((ext_vector_type(2)))  unsigned int u32x2;
typedef __attribute__((ext_vector_type(4)))  unsigned int u32x4;

__device__ __forceinline__ uint16_t f32_to_bf16(float f) {
  uint32_t u = __float_as_uint(f);
  u += 0x7FFFu + ((u >> 16) & 1u);           // round-to-nearest-even
  return (uint16_t)(u >> 16);
}

__device__ __forceinline__ uint32_t cvtpk_bf16(float lo, float hi) {
  uint32_t r;
  asm("v_cvt_pk_bf16_f32 %0, %1, %2" : "=v"(r) : "v"(lo), "v"(hi));
  return r;
}

#if __has_builtin(__builtin_amdgcn_exp2f)
#define EXP2F(x) __builtin_amdgcn_exp2f(x)
#else
#define EXP2F(x) exp2f(x)
#endif

#define ZERO16 {0.f,0.f,0.f,0.f,0.f,0.f,0.f,0.f,0.f,0.f,0.f,0.f,0.f,0.f,0.f,0.f}

// XOR swizzle for [rows][64] bf16 LDS tiles (idx in ushort units).
__device__ __forceinline__ int swz64(int idx) {
  return idx ^ (((idx >> 6) & 7) << 3);
}

// async global->LDS, 16B per lane; dest must be linear (wave base + lane*16)
__device__ __forceinline__ void gload16(uint16_t* lds, const uint16_t* g) {
  __builtin_amdgcn_global_load_lds((const __attribute__((address_space(1))) void*)g,
                                   (__attribute__((address_space(3))) void*)lds, 16, 0, 0);
}

// reg-staged fp32 chunk -> bf16x8 in LDS (bit-identical image to the gload16 path:
// same source elements, same linear dest, RNE rounding via v_cvt_pk_bf16_f32)
__device__ __forceinline__ void stage_cvt(uint16_t* lds_dst, const float* src) {
  f32x4 f0 = *reinterpret_cast<const f32x4*>(src);
  f32x4 f1 = *reinterpret_cast<const f32x4*>(src + 4);
  u32x4 uu;
  uu.x = cvtpk_bf16(f0[0], f0[1]);
  uu.y = cvtpk_bf16(f0[2], f0[3]);
  uu.z = cvtpk_bf16(f1[0], f1[1]);
  uu.w = cvtpk_bf16(f1[2], f1[3]);
  *reinterpret_cast<u32x4*>(lds_dst) = uu;
}

// ---------------- QKV GEMM: fp32 inputs, fused cvt in staging; BM=128, BN=64, 1152 blocks ----------------
__global__ __launch_bounds__(256) void qkv_gemm(const float* __restrict__ A32,
                                                const float* __restrict__ W32,
                                                const float* __restrict__ bias,
                                                uint16_t* __restrict__ qb,
                                                uint16_t* __restrict__ kb,
                                                uint16_t* __restrict__ vb) {
  __shared__ __align__(16) uint16_t As[128 * 64];
  __shared__ __align__(16) uint16_t Bs[64 * 64];
  const int t    = threadIdx.x;
  const int lane = t & 63;
  const int wv   = t >> 6;
  const int wr   = wv >> 1, wc = wv & 1;
  // bijective XCD swizzle: 1152 = 8 * 144
  const int wg   = (blockIdx.x & 7) * 144 + (blockIdx.x >> 3);
  const int bm   = wg & 31;                  // 32 M tiles (128 rows)
  const int bn   = wg >> 5;                  // 36 N tiles (64 cols)

  const float* Ag = A32 + (size_t)bm * 128 * 768;
  const float* Wg = W32 + (size_t)bn * 64 * 768;

  // per-thread staging source offsets (same chunk->element mapping as gload16 path)
  int aoff[4], lofA[4];
#pragma unroll
  for (int j = 0; j < 4; j++) {
    int p = j * 256 + t, r = p >> 3, x = p & 7;
    int scol = (x ^ (r & 7)) << 3;
    aoff[j] = r * 768 + scol;
    lofA[j] = p * 8;
  }
  int woff[2], lofB[2];
#pragma unroll
  for (int j = 0; j < 2; j++) {
    int p = j * 256 + t, r = p >> 3, x = p & 7;
    int scol = (x ^ (r & 7)) << 3;
    woff[j] = r * 768 + scol;
    lofB[j] = p * 8;
  }

  f32x4 zf = {0.f, 0.f, 0.f, 0.f};
  f32x4 acc[4][2];
#pragma unroll
  for (int m = 0; m < 4; m++)
#pragma unroll
    for (int n = 0; n < 2; n++) acc[m][n] = zf;

  for (int k0 = 0; k0 < 768; k0 += 64) {
#pragma unroll
    for (int j = 0; j < 4; j++)
      stage_cvt(&As[lofA[j]], Ag + aoff[j] + k0);
#pragma unroll
    for (int j = 0; j < 2; j++)
      stage_cvt(&Bs[lofB[j]], Wg + woff[j] + k0);
    __syncthreads();
#pragma unroll
    for (int kk = 0; kk < 2; kk++) {
      const int kc = kk * 32 + (lane >> 4) * 8;
      bf16x8 af[4], bf[2];
#pragma unroll
      for (int m = 0; m < 4; m++)
        af[m] = *reinterpret_cast<const bf16x8*>(&As[swz64((wr * 64 + m * 16 + (lane & 15)) * 64 + kc)]);
#pragma unroll
      for (int n = 0; n < 2; n++)
        bf[n] = *reinterpret_cast<const bf16x8*>(&Bs[swz64((wc * 32 + n * 16 + (lane & 15)) * 64 + kc)]);
#pragma unroll
      for (int m = 0; m < 4; m++)
#pragma unroll
        for (int n = 0; n < 2; n++)
          acc[m][n] = __builtin_amdgcn_mfma_f32_16x16x32_bf16(af[m], bf[n], acc[m][n], 0, 0, 0);
    }
    __syncthreads();
  }

#pragma unroll
  for (int n = 0; n < 2; n++) {
    const int f = bn * 64 + wc * 32 + n * 16 + (lane & 15);
    const float bv  = bias[f];
    const int  c    = f / 768;
    const int  rem  = f % 768;
    const int  h    = rem >> 6, d = rem & 63;
    const float scl = (c == 0) ? 0.125f * 1.44269504f : 1.0f;  // SCALE*log2e folded into Q
#pragma unroll
    for (int m = 0; m < 4; m++) {
#pragma unroll
      for (int r = 0; r < 4; r++) {
        int i = bm * 128 + wr * 64 + m * 16 + (lane >> 4) * 4 + r;
        int b = i >> 11, s = i & 2047;
        uint16_t val = f32_to_bf16((acc[m][n][r] + bv) * scl);
        if (c == 0)
          qb[(((size_t)b * NHEAD + h) * S_LEN + s) * HDIM + d] = val;
        else if (c == 1)
          kb[(((size_t)b * NHEAD + h) * S_LEN + s) * HDIM + d] = val;
        else
          vb[(((size_t)b * NHEAD + h) * HDIM + d) * S_LEN + s] = val;   // V transposed
      }
    }
  }
}

// ---------------- Flash attention (verified r12): counted-vmcnt + unroll-2 + setprio ----------------
__global__ __launch_bounds__(256, 3) void attn_kernel(const uint16_t* __restrict__ Q,   // [BH][S][D], pre-scaled
                                                      const uint16_t* __restrict__ Kb,  // [BH][S][D]
                                                      const uint16_t* __restrict__ Vb,  // [BH][D][S]
                                                      const int* __restrict__ mask,     // [B][S]
                                                      uint16_t* __restrict__ X) {       // [B][S][E] bf16
  __shared__ __align__(16) uint16_t Kd[2][64 * 64];
  __shared__ __align__(16) uint16_t Vd[2][64 * 64];   // [d][key]
  __shared__ __align__(16) float    mb_s[S_LEN];      // per-block mask bias, whole row
  __shared__ float Lc[2][32];

  const int t    = threadIdx.x;
  const int lane = t & 63;
  const int hl   = lane >> 5;                   // lane half
  const int q31  = lane & 31;
  const int wv   = t >> 6;
  const int qg   = wv & 1;                      // q-group
  const int kh   = wv >> 1;                     // key-half
  // bijective XCD swizzle: 768 = 8 * 96; each XCD gets 3 whole heads (L2-fit K/V)
  const int wg   = (blockIdx.x & 7) * 96 + (blockIdx.x >> 3);
  const int qblk = wg & 31;
  const int bh   = wg >> 5;
  const int b    = bh / NHEAD, hd = bh % NHEAD;

  const uint16_t* Qh = Q  + (size_t)bh * S_LEN * HDIM;
  const uint16_t* Kh = Kb + (size_t)bh * S_LEN * HDIM;
  const uint16_t* Vh = Vb + (size_t)bh * HDIM * S_LEN;
  const int q0 = qblk * 64 + qg * 32;

  // one-time mask -> float bias preload (8 keys/thread, coalesced)
  {
    int4 m0 = *reinterpret_cast<const int4*>(&mask[b * S_LEN + t * 8]);
    int4 m1 = *reinterpret_cast<const int4*>(&mask[b * S_LEN + t * 8 + 4]);
    float4 f0, f1;
    f0.x = m0.x ? -1e30f : 0.0f; f0.y = m0.y ? -1e30f : 0.0f;
    f0.z = m0.z ? -1e30f : 0.0f; f0.w = m0.w ? -1e30f : 0.0f;
    f1.x = m1.x ? -1e30f : 0.0f; f1.y = m1.y ? -1e30f : 0.0f;
    f1.z = m1.z ? -1e30f : 0.0f; f1.w = m1.w ? -1e30f : 0.0f;
    *reinterpret_cast<float4*>(&mb_s[t * 8])     = f0;
    *reinterpret_cast<float4*>(&mb_s[t * 8 + 4]) = f1;
  }

  // Q as B-fragments: col=q31, k=d=16s+8hl+j
  bf16x8 qf[4];
#pragma unroll
  for (int s = 0; s < 4; s++)
    qf[s] = *reinterpret_cast<const bf16x8*>(Qh + (size_t)(q0 + q31) * HDIM + 16 * s + 8 * hl);

  f32x16 oacc[2] = {ZERO16, ZERO16};
  float lsum = 0.f;

  const uint16_t* kga[2]; const uint16_t* vga[2]; int lof[2];
#pragma unroll
  for (int j = 0; j < 2; j++) {
    int p = j * 256 + t, r = p >> 3, x = p & 7;
    int scol = (x ^ (r & 7)) << 3;
    kga[j] = Kh + (size_t)r * HDIM + scol;
    vga[j] = Vh + (size_t)r * S_LEN + scol;
    lof[j] = p * 8;
  }
  auto stage = [&](int nb, int it2) {   // 4 vmem instructions per thread
#pragma unroll
    for (int j = 0; j < 2; j++) {
      gload16(&Kd[nb][lof[j]], kga[j] + it2 * 64 * HDIM);
      gload16(&Vd[nb][lof[j]], vga[j] + it2 * 64);
    }
  };

  stage(0, 0);
  __syncthreads();                       // prologue: full drain, mask + buf0 ready

#pragma unroll 2
  for (int it = 0; it < 32; ++it) {
    const int cur = it & 1;              // compile-time 0/1 after unroll-2
    __builtin_amdgcn_s_barrier();        // A: all waves done compute(it-1) -> buf cur^1 free
    __builtin_amdgcn_sched_barrier(0);
    if (it + 1 < 32) {
      stage(cur ^ 1, it + 1);            // next-tile loads: stay in flight across B
      asm volatile("s_waitcnt vmcnt(4)" ::: "memory");   // my tile-it loads done
    } else {
      asm volatile("s_waitcnt vmcnt(0)" ::: "memory");
    }
    __builtin_amdgcn_s_barrier();        // B: buf cur staged block-wide
    __builtin_amdgcn_sched_barrier(0);

    // QK^T (swapped): scc[reg] = S[key_loc=(reg&3)+8*(reg>>2)+4*hl][q31]
    f32x16 scc = ZERO16;
    __builtin_amdgcn_s_setprio(1);
#pragma unroll
    for (int s = 0; s < 4; s++) {
      bf16x8 kf = *reinterpret_cast<const bf16x8*>(&Kd[cur][swz64((kh * 32 + q31) * 64 + 16 * s + 8 * hl)]);
      scc = __builtin_amdgcn_mfma_f32_32x32x16_bf16(kf, qf[s], scc, 0, 0, 0);
    }
    __builtin_amdgcn_s_setprio(0);

    // mask + exp2 + per-lane sum; pack pairs to bf16
    uint32_t w[4][2];
#pragma unroll
    for (int s2 = 0; s2 < 4; s2++) {
      f32x4 mbv = *reinterpret_cast<const f32x4*>(&mb_s[it * 64 + kh * 32 + s2 * 8 + hl * 4]);
      float p0 = EXP2F(scc[4 * s2 + 0] + mbv[0]);
      float p1 = EXP2F(scc[4 * s2 + 1] + mbv[1]);
      float p2 = EXP2F(scc[4 * s2 + 2] + mbv[2]);
      float p3 = EXP2F(scc[4 * s2 + 3] + mbv[3]);
      lsum += (p0 + p1) + (p2 + p3);
      w[s2][0] = cvtpk_bf16(p0, p1);
      w[s2][1] = cvtpk_bf16(p2, p3);
    }

    // redistribute P into PV B-fragments: pb[ks][j] = P[16ks+8hl+j][q31]
    bf16x8 pb[2];
#pragma unroll
    for (int ks = 0; ks < 2; ks++) {
      u32x2 r0 = __builtin_amdgcn_permlane32_swap(w[2 * ks][0], w[2 * ks + 1][0], false, false);
      u32x2 r1 = __builtin_amdgcn_permlane32_swap(w[2 * ks][1], w[2 * ks + 1][1], false, false);
      u32x4 uu;
      uu.x = r0.x; uu.y = r1.x; uu.z = r0.y; uu.w = r1.y;
      pb[ks] = __builtin_bit_cast(bf16x8, uu);
    }

    // PV (swapped): O^T[d][q] += V^T[d][k] * P[k][q]
    __builtin_amdgcn_s_setprio(1);
#pragma unroll
    for (int mt = 0; mt < 2; mt++)
#pragma unroll
      for (int ks = 0; ks < 2; ks++) {
        bf16x8 vf = *reinterpret_cast<const bf16x8*>(&Vd[cur][swz64((mt * 32 + q31) * 64 + kh * 32 + ks * 16 + hl * 8)]);
        oacc[mt] = __builtin_amdgcn_mfma_f32_32x32x16_bf16(vf, pb[ks], oacc[mt], 0, 0, 0);
      }
    __builtin_amdgcn_s_setprio(0);
  }

  // per-wave row sum for column q31
  lsum += __shfl_xor(lsum, 32);

  // combine key-half partials: kh=1 writes O^T and l, kh=0 finishes
  // (Oc aliases buffer 0; last read of buffer 0 was it=30, ordered by barrier B of it=31)
  float* Oc = qg ? (float*)&Vd[0][0] : (float*)&Kd[0][0];   // [64 d][32 q]
  if (kh == 1) {
#pragma unroll
    for (int mt = 0; mt < 2; mt++)
#pragma unroll
      for (int e = 0; e < 16; e++) {
        int d = mt * 32 + (e & 3) + (e >> 2) * 8 + hl * 4;
        Oc[d * 32 + q31] = oacc[mt][e];
      }
    if (hl == 0) Lc[qg][q31] = lsum;
  }
  __syncthreads();
  if (kh == 0) {
    float linv = 1.0f / (lsum + Lc[qg][q31]);
    uint16_t* Xr = X + ((size_t)b * S_LEN + q0 + q31) * EMB + hd * HDIM;
#pragma unroll
    for (int mt = 0; mt < 2; mt++)
#pragma unroll
      for (int s2 = 0; s2 < 4; s2++) {
        int d0 = mt * 32 + s2 * 8 + hl * 4;
        float v0 = (oacc[mt][4 * s2 + 0] + Oc[(d0 + 0) * 32 + q31]) * linv;
        float v1 = (oacc[mt][4 * s2 + 1] + Oc[(d0 + 1) * 32 + q31]) * linv;
        float v2 = (oacc[mt][4 * s2 + 2] + Oc[(d0 + 2) * 32 + q31]) * linv;
        float v3 = (oacc[mt][4 * s2 + 3] + Oc[(d0 + 3) * 32 + q31]) * linv;
        uint2 ww;
        ww.x = cvtpk_bf16(v0, v1);
        ww.y = cvtpk_bf16(v2, v3);
        *reinterpret_cast<uint2*>(Xr + d0) = ww;
      }
  }
}

// ---------------- Proj GEMM: A=x_bf (bf16, gload16), W=fp32 reg-staged cvt; 768 blocks ----------------
__global__ __launch_bounds__(256) void proj_gemm(const uint16_t* __restrict__ A,
                                                 const float* __restrict__ W32,
                                                 const float* __restrict__ bias,
                                                 float* __restrict__ out) {
  __shared__ __align__(16) uint16_t As[64 * 64];
  __shared__ __align__(16) uint16_t Bs[64 * 64];
  const int t    = threadIdx.x;
  const int lane = t & 63;
  const int wv   = t >> 6;
  const int wr   = wv >> 1, wc = wv & 1;
  const int bm   = blockIdx.x & 63;          // 64 M tiles
  const int bn   = blockIdx.x >> 6;          // 12 N tiles

  const uint16_t* Ag = A   + (size_t)bm * 64 * 768;
  const float*    Wg = W32 + (size_t)bn * 64 * 768;

  f32x4 zf = {0.f, 0.f, 0.f, 0.f};
  f32x4 acc[2][2];
#pragma unroll
  for (int m = 0; m < 2; m++)
#pragma unroll
    for (int n = 0; n < 2; n++) acc[m][n] = zf;

  for (int k0 = 0; k0 < 768; k0 += 64) {
#pragma unroll
    for (int j = 0; j < 2; j++) {
      int p = j * 256 + t;                   // chunk 0..511
      int r = p >> 3, x = p & 7;
      int scol = (x ^ (r & 7)) << 3;
      gload16(&As[p * 8], Ag + (size_t)r * 768 + k0 + scol);
      stage_cvt(&Bs[p * 8], Wg + (size_t)r * 768 + k0 + scol);
    }
    __syncthreads();
#pragma unroll
    for (int kk = 0; kk < 2; kk++) {
      const int kc = kk * 32 + (lane >> 4) * 8;
      bf16x8 af[2], bf[2];
#pragma unroll
      for (int m = 0; m < 2; m++)
        af[m] = *reinterpret_cast<const bf16x8*>(&As[swz64((wr * 32 + m * 16 + (lane & 15)) * 64 + kc)]);
#pragma unroll
      for (int n = 0; n < 2; n++)
        bf[n] = *reinterpret_cast<const bf16x8*>(&Bs[swz64((wc * 32 + n * 16 + (lane & 15)) * 64 + kc)]);
#pragma unroll
      for (int m = 0; m < 2; m++)
#pragma unroll
        for (int n = 0; n < 2; n++)
          acc[m][n] = __builtin_amdgcn_mfma_f32_16x16x32_bf16(af[m], bf[n], acc[m][n], 0, 0, 0);
    }
    __syncthreads();
  }

#pragma unroll
  for (int n = 0; n < 2; n++) {
    const int f = bn * 64 + wc * 32 + n * 16 + (lane & 15);
    const float bv = bias[f];
#pragma unroll
    for (int m = 0; m < 2; m++)
#pragma unroll
      for (int r = 0; r < 4; r++) {
        int i = bm * 64 + wr * 32 + m * 16 + (lane >> 4) * 4 + r;
        out[(size_t)i * 768 + f] = acc[m][n][r] + bv;
      }
  }
}

extern "C" void kernel_launch(void* const* d_in, const int* in_sizes, int n_in,
                              void* d_out, int out_size, void* d_ws, size_t ws_size,
                              hipStream_t stream) {
  const float* inputs = (const float*)d_in[0];
  const int*   mask   = (const int*)d_in[1];
  const float* w_qkv  = (const float*)d_in[2];
  const float* b_qkv  = (const float*)d_in[3];
  const float* w_proj = (const float*)d_in[4];
  const float* b_proj = (const float*)d_in[5];
  float* out = (float*)d_out;

  uint16_t* q_bf  = (uint16_t*)d_ws;                    // 24*2048*64
  uint16_t* k_bf  = q_bf  + (size_t)24 * 2048 * 64;
  uint16_t* v_bf  = k_bf  + (size_t)24 * 2048 * 64;     // stored [B,H,D,S]
  uint16_t* x_bf  = v_bf  + (size_t)24 * 2048 * 64;     // 4096*768

  qkv_gemm<<<32 * 36, 256, 0, stream>>>(inputs, w_qkv, b_qkv, q_bf, k_bf, v_bf);
  attn_kernel<<<24 * 32, 256, 0, stream>>>(q_bf, k_bf, v_bf, mask, x_bf);
  proj_gemm<<<64 * 12, 256, 0, stream>>>(x_bf, w_proj, b_proj, out);
}

// Round 15
// 108.175 us; speedup vs baseline: 1.0835x; 1.0835x over previous
//
#include <hip/hip_runtime.h>
#include <stdint.h>

#define S_LEN 2048
#define EMB   768
#define NHEAD 12
#define HDIM  64

typedef __attribute__((ext_vector_type(8)))  __bf16       bf16x8;
typedef __attribute__((ext_vector_type(4)))  float        f32x4;
typedef __attribute__((ext_vector_type(16))) float        f32x16;
typedef __attribute__((ext_vector_type(2)))  unsigned int u32x2;
typedef __attribute__((ext_vector_type(4)))  unsigned int u32x4;

__device__ __forceinline__ uint16_t f32_to_bf16(float f) {
  uint32_t u = __float_as_uint(f);
  u += 0x7FFFu + ((u >> 16) & 1u);           // round-to-nearest-even
  return (uint16_t)(u >> 16);
}

__device__ __forceinline__ uint32_t cvtpk_bf16(float lo, float hi) {
  uint32_t r;
  asm("v_cvt_pk_bf16_f32 %0, %1, %2" : "=v"(r) : "v"(lo), "v"(hi));
  return r;
}

#if __has_builtin(__builtin_amdgcn_exp2f)
#define EXP2F(x) __builtin_amdgcn_exp2f(x)
#else
#define EXP2F(x) exp2f(x)
#endif

#define ZERO16 {0.f,0.f,0.f,0.f,0.f,0.f,0.f,0.f,0.f,0.f,0.f,0.f,0.f,0.f,0.f,0.f}

// XOR swizzle for [rows][64] bf16 LDS tiles (idx in ushort units).
__device__ __forceinline__ int swz64(int idx) {
  return idx ^ (((idx >> 6) & 7) << 3);
}

// async global->LDS, 16B per lane; dest must be linear (wave base + lane*16)
__device__ __forceinline__ void gload16(uint16_t* lds, const uint16_t* g) {
  __builtin_amdgcn_global_load_lds((const __attribute__((address_space(1))) void*)g,
                                   (__attribute__((address_space(3))) void*)lds, 16, 0, 0);
}

// ---------------- fused fp32 -> bf16 convert (verified r12) ----------------
__global__ __launch_bounds__(256) void cvt_all(const float4* __restrict__ i0, ushort4* __restrict__ o0, int n0,
                                               const float4* __restrict__ i1, ushort4* __restrict__ o1, int n1,
                                               const float4* __restrict__ i2, ushort4* __restrict__ o2, int n2) {
  int gid = blockIdx.x * blockDim.x + threadIdx.x;
  const float4* src;
  ushort4* dst;
  int idx;
  if (gid < n0)           { src = i0; dst = o0; idx = gid; }
  else if (gid < n0 + n1) { src = i1; dst = o1; idx = gid - n0; }
  else if (gid < n0 + n1 + n2) { src = i2; dst = o2; idx = gid - n0 - n1; }
  else return;
  float4 v = src[idx];
  ushort4 o;
  o.x = f32_to_bf16(v.x); o.y = f32_to_bf16(v.y);
  o.z = f32_to_bf16(v.z); o.w = f32_to_bf16(v.w);
  dst[idx] = o;
}

// ---------------- mask scan: compacted key indices + tail bias + K/V pad zeroing ----------------
// One block per batch. cpos[b][s] = compacted index (or -1 if masked); nt[b] = key
// tiles after compaction; mbc[b][j] = 0 (j < nb) else -1e30 (tail pad). Pad rows of
// K (and pad cols of V^T) are zeroed so pad MFMA inputs are exact 0 (never garbage).
__global__ __launch_bounds__(256) void mask_scan(const int* __restrict__ mask,
                                                 int* __restrict__ cpos,
                                                 float* __restrict__ mbc,
                                                 int* __restrict__ ntp,
                                                 uint16_t* __restrict__ kb,
                                                 uint16_t* __restrict__ vb) {
  const int b = blockIdx.x;
  const int t = threadIdx.x;
  __shared__ int part[257];
  int m[8], u = 0;
#pragma unroll
  for (int j = 0; j < 8; j++) {
    m[j] = mask[b * S_LEN + t * 8 + j];
    u += (m[j] == 0);
  }
  part[t] = u;
  __syncthreads();
  if (t == 0) {
    int run = 0;
    for (int i = 0; i < 256; i++) { int v = part[i]; part[i] = run; run += v; }
    part[256] = run;
  }
  __syncthreads();
  const int nb = part[256];
  int base = part[t];
#pragma unroll
  for (int j = 0; j < 8; j++) {
    int sc = (m[j] == 0) ? base : -1;
    if (m[j] == 0) base++;
    cpos[b * S_LEN + t * 8 + j] = sc;
    mbc[b * S_LEN + t * 8 + j] = ((t * 8 + j) < nb) ? 0.0f : -1e30f;
  }
  const int padN = (nb + 63) & ~63;
  if (t == 0) ntp[b] = padN >> 6;
  const int npad = padN - nb;
  if (npad > 0) {
    const int tot = npad * NHEAD * HDIM;
    for (int idx = t; idx < tot; idx += 256) {
      int d   = idx & (HDIM - 1);
      int rem = idx >> 6;
      int row = rem % npad;
      int h   = rem / npad;
      kb[(((size_t)b * NHEAD + h) * S_LEN + nb + row) * HDIM + d] = 0;
      vb[(((size_t)b * NHEAD + h) * HDIM + d) * S_LEN + nb + row] = 0;
    }
  }
}

// ---------------- QKV GEMM (verified r12 loop): BM=128, BN=64, 1152 blocks ----------------
// Epilogue: K/V scattered through cpos (compacted, masked keys skipped); Q unchanged.
__global__ __launch_bounds__(256) void qkv_gemm(const uint16_t* __restrict__ A,
                                                const uint16_t* __restrict__ W,
                                                const float* __restrict__ bias,
                                                const int* __restrict__ cpos,
                                                uint16_t* __restrict__ qb,
                                                uint16_t* __restrict__ kb,
                                                uint16_t* __restrict__ vb) {
  __shared__ __align__(16) uint16_t As[128 * 64];
  __shared__ __align__(16) uint16_t Bs[64 * 64];
  const int t    = threadIdx.x;
  const int lane = t & 63;
  const int wv   = t >> 6;
  const int wr   = wv >> 1, wc = wv & 1;
  // bijective XCD swizzle: 1152 = 8 * 144
  const int wg   = (blockIdx.x & 7) * 144 + (blockIdx.x >> 3);
  const int bm   = wg & 31;                  // 32 M tiles (128 rows)
  const int bn   = wg >> 5;                  // 36 N tiles (64 cols)

  const uint16_t* Ag = A + (size_t)bm * 128 * 768;
  const uint16_t* Wg = W + (size_t)bn * 64 * 768;

  f32x4 zf = {0.f, 0.f, 0.f, 0.f};
  f32x4 acc[4][2];
#pragma unroll
  for (int m = 0; m < 4; m++)
#pragma unroll
    for (int n = 0; n < 2; n++) acc[m][n] = zf;

  for (int k0 = 0; k0 < 768; k0 += 64) {
#pragma unroll
    for (int j = 0; j < 4; j++) {            // A tile: 1024 chunks
      int p = j * 256 + t;
      int r = p >> 3, x = p & 7;
      int scol = (x ^ (r & 7)) << 3;
      gload16(&As[p * 8], Ag + (size_t)r * 768 + k0 + scol);
    }
#pragma unroll
    for (int j = 0; j < 2; j++) {            // B tile: 512 chunks
      int p = j * 256 + t;
      int r = p >> 3, x = p & 7;
      int scol = (x ^ (r & 7)) << 3;
      gload16(&Bs[p * 8], Wg + (size_t)r * 768 + k0 + scol);
    }
    __syncthreads();
#pragma unroll
    for (int kk = 0; kk < 2; kk++) {
      const int kc = kk * 32 + (lane >> 4) * 8;
      bf16x8 af[4], bf[2];
#pragma unroll
      for (int m = 0; m < 4; m++)
        af[m] = *reinterpret_cast<const bf16x8*>(&As[swz64((wr * 64 + m * 16 + (lane & 15)) * 64 + kc)]);
#pragma unroll
      for (int n = 0; n < 2; n++)
        bf[n] = *reinterpret_cast<const bf16x8*>(&Bs[swz64((wc * 32 + n * 16 + (lane & 15)) * 64 + kc)]);
#pragma unroll
      for (int m = 0; m < 4; m++)
#pragma unroll
        for (int n = 0; n < 2; n++)
          acc[m][n] = __builtin_amdgcn_mfma_f32_16x16x32_bf16(af[m], bf[n], acc[m][n], 0, 0, 0);
    }
    __syncthreads();
  }

#pragma unroll
  for (int n = 0; n < 2; n++) {
    const int f = bn * 64 + wc * 32 + n * 16 + (lane & 15);
    const float bv  = bias[f];
    const int  c    = f / 768;
    const int  rem  = f % 768;
    const int  h    = rem >> 6, d = rem & 63;
    const float scl = (c == 0) ? 0.125f * 1.44269504f : 1.0f;  // SCALE*log2e folded into Q
#pragma unroll
    for (int m = 0; m < 4; m++) {
#pragma unroll
      for (int r = 0; r < 4; r++) {
        int i = bm * 128 + wr * 64 + m * 16 + (lane >> 4) * 4 + r;
        int b = i >> 11, s = i & 2047;
        uint16_t val = f32_to_bf16((acc[m][n][r] + bv) * scl);
        if (c == 0) {
          qb[(((size_t)b * NHEAD + h) * S_LEN + s) * HDIM + d] = val;
        } else {
          int sc = cpos[b * S_LEN + s];
          if (sc >= 0) {
            if (c == 1)
              kb[(((size_t)b * NHEAD + h) * S_LEN + sc) * HDIM + d] = val;
            else
              vb[(((size_t)b * NHEAD + h) * HDIM + d) * S_LEN + sc] = val;  // V transposed
          }
        }
      }
    }
  }
}

// ---------------- Flash attention (r12 body): compacted keys, runtime tile count ----------------
__global__ __launch_bounds__(256, 3) void attn_kernel(const uint16_t* __restrict__ Q,   // [BH][S][D], pre-scaled
                                                      const uint16_t* __restrict__ Kb,  // [BH][Sc][D] compacted
                                                      const uint16_t* __restrict__ Vb,  // [BH][D][Sc] compacted
                                                      const float* __restrict__ mbc,    // [B][S] compact bias
                                                      const int* __restrict__ ntp,      // [B] tile count
                                                      uint16_t* __restrict__ X) {       // [B][S][E] bf16
  __shared__ __align__(16) uint16_t Kd[2][64 * 64];
  __shared__ __align__(16) uint16_t Vd[2][64 * 64];   // [d][key]
  __shared__ __align__(16) float    mb_s[S_LEN];
  __shared__ float Lc[2][32];

  const int t    = threadIdx.x;
  const int lane = t & 63;
  const int hl   = lane >> 5;                   // lane half
  const int q31  = lane & 31;
  const int wv   = t >> 6;
  const int qg   = wv & 1;                      // q-group
  const int kh   = wv >> 1;                     // key-half
  // bijective XCD swizzle: 768 = 8 * 96; each XCD gets 3 whole heads (L2-fit K/V)
  const int wg   = (blockIdx.x & 7) * 96 + (blockIdx.x >> 3);
  const int qblk = wg & 31;
  const int bh   = wg >> 5;
  const int b    = bh / NHEAD, hd = bh % NHEAD;

  const uint16_t* Qh = Q  + (size_t)bh * S_LEN * HDIM;
  const uint16_t* Kh = Kb + (size_t)bh * S_LEN * HDIM;
  const uint16_t* Vh = Vb + (size_t)bh * HDIM * S_LEN;
  const int q0 = qblk * 64 + qg * 32;
  const int nt = ntp[b];

  // compact bias preload (8 keys/thread, coalesced float4)
  {
    float4 f0 = *reinterpret_cast<const float4*>(&mbc[b * S_LEN + t * 8]);
    float4 f1 = *reinterpret_cast<const float4*>(&mbc[b * S_LEN + t * 8 + 4]);
    *reinterpret_cast<float4*>(&mb_s[t * 8])     = f0;
    *reinterpret_cast<float4*>(&mb_s[t * 8 + 4]) = f1;
  }

  // Q as B-fragments: col=q31, k=d=16s+8hl+j
  bf16x8 qf[4];
#pragma unroll
  for (int s = 0; s < 4; s++)
    qf[s] = *reinterpret_cast<const bf16x8*>(Qh + (size_t)(q0 + q31) * HDIM + 16 * s + 8 * hl);

  f32x16 oacc[2] = {ZERO16, ZERO16};
  float lsum = 0.f;

  const uint16_t* kga[2]; const uint16_t* vga[2]; int lof[2];
#pragma unroll
  for (int j = 0; j < 2; j++) {
    int p = j * 256 + t, r = p >> 3, x = p & 7;
    int scol = (x ^ (r & 7)) << 3;
    kga[j] = Kh + (size_t)r * HDIM + scol;
    vga[j] = Vh + (size_t)r * S_LEN + scol;
    lof[j] = p * 8;
  }
  auto stage = [&](int nb2, int it2) {   // 4 vmem instructions per thread
#pragma unroll
    for (int j = 0; j < 2; j++) {
      gload16(&Kd[nb2][lof[j]], kga[j] + it2 * 64 * HDIM);
      gload16(&Vd[nb2][lof[j]], vga[j] + it2 * 64);
    }
  };

  stage(0, 0);
  __syncthreads();                       // prologue: full drain, bias + buf0 ready

#pragma unroll 2
  for (int it = 0; it < nt; ++it) {
    const int cur = it & 1;
    __builtin_amdgcn_s_barrier();        // A: all waves done compute(it-1) -> buf cur^1 free
    __builtin_amdgcn_sched_barrier(0);
    if (it + 1 < nt) {
      stage(cur ^ 1, it + 1);            // next-tile loads: stay in flight across B
      asm volatile("s_waitcnt vmcnt(4)" ::: "memory");   // my tile-it loads done
    } else {
      asm volatile("s_waitcnt vmcnt(0)" ::: "memory");
    }
    __builtin_amdgcn_s_barrier();        // B: buf cur staged block-wide
    __builtin_amdgcn_sched_barrier(0);

    // QK^T (swapped): scc[reg] = S[key_loc=(reg&3)+8*(reg>>2)+4*hl][q31]
    f32x16 scc = ZERO16;
    __builtin_amdgcn_s_setprio(1);
#pragma unroll
    for (int s = 0; s < 4; s++) {
      bf16x8 kf = *reinterpret_cast<const bf16x8*>(&Kd[cur][swz64((kh * 32 + q31) * 64 + 16 * s + 8 * hl)]);
      scc = __builtin_amdgcn_mfma_f32_32x32x16_bf16(kf, qf[s], scc, 0, 0, 0);
    }
    __builtin_amdgcn_s_setprio(0);

    // tail bias + exp2 + per-lane sum; pack pairs to bf16
    uint32_t w[4][2];
#pragma unroll
    for (int s2 = 0; s2 < 4; s2++) {
      f32x4 mbv = *reinterpret_cast<const f32x4*>(&mb_s[it * 64 + kh * 32 + s2 * 8 + hl * 4]);
      float p0 = EXP2F(scc[4 * s2 + 0] + mbv[0]);
      float p1 = EXP2F(scc[4 * s2 + 1] + mbv[1]);
      float p2 = EXP2F(scc[4 * s2 + 2] + mbv[2]);
      float p3 = EXP2F(scc[4 * s2 + 3] + mbv[3]);
      lsum += (p0 + p1) + (p2 + p3);
      w[s2][0] = cvtpk_bf16(p0, p1);
      w[s2][1] = cvtpk_bf16(p2, p3);
    }

    // redistribute P into PV B-fragments: pb[ks][j] = P[16ks+8hl+j][q31]
    bf16x8 pb[2];
#pragma unroll
    for (int ks = 0; ks < 2; ks++) {
      u32x2 r0 = __builtin_amdgcn_permlane32_swap(w[2 * ks][0], w[2 * ks + 1][0], false, false);
      u32x2 r1 = __builtin_amdgcn_permlane32_swap(w[2 * ks][1], w[2 * ks + 1][1], false, false);
      u32x4 uu;
      uu.x = r0.x; uu.y = r1.x; uu.z = r0.y; uu.w = r1.y;
      pb[ks] = __builtin_bit_cast(bf16x8, uu);
    }

    // PV (swapped): O^T[d][q] += V^T[d][k] * P[k][q]
    __builtin_amdgcn_s_setprio(1);
#pragma unroll
    for (int mt = 0; mt < 2; mt++)
#pragma unroll
      for (int ks = 0; ks < 2; ks++) {
        bf16x8 vf = *reinterpret_cast<const bf16x8*>(&Vd[cur][swz64((mt * 32 + q31) * 64 + kh * 32 + ks * 16 + hl * 8)]);
        oacc[mt] = __builtin_amdgcn_mfma_f32_32x32x16_bf16(vf, pb[ks], oacc[mt], 0, 0, 0);
      }
    __builtin_amdgcn_s_setprio(0);
  }

  // per-wave row sum for column q31
  lsum += __shfl_xor(lsum, 32);

  __syncthreads();   // nt may be odd: ensure all waves done reading buf0 before Oc alias write

  // combine key-half partials: kh=1 writes O^T and l, kh=0 finishes
  float* Oc = qg ? (float*)&Vd[0][0] : (float*)&Kd[0][0];   // [64 d][32 q]
  if (kh == 1) {
#pragma unroll
    for (int mt = 0; mt < 2; mt++)
#pragma unroll
      for (int e = 0; e < 16; e++) {
        int d = mt * 32 + (e & 3) + (e >> 2) * 8 + hl * 4;
        Oc[d * 32 + q31] = oacc[mt][e];
      }
    if (hl == 0) Lc[qg][q31] = lsum;
  }
  __syncthreads();
  if (kh == 0) {
    float linv = 1.0f / (lsum + Lc[qg][q31]);
    uint16_t* Xr = X + ((size_t)b * S_LEN + q0 + q31) * EMB + hd * HDIM;
#pragma unroll
    for (int mt = 0; mt < 2; mt++)
#pragma unroll
      for (int s2 = 0; s2 < 4; s2++) {
        int d0 = mt * 32 + s2 * 8 + hl * 4;
        float v0 = (oacc[mt][4 * s2 + 0] + Oc[(d0 + 0) * 32 + q31]) * linv;
        float v1 = (oacc[mt][4 * s2 + 1] + Oc[(d0 + 1) * 32 + q31]) * linv;
        float v2 = (oacc[mt][4 * s2 + 2] + Oc[(d0 + 2) * 32 + q31]) * linv;
        float v3 = (oacc[mt][4 * s2 + 3] + Oc[(d0 + 3) * 32 + q31]) * linv;
        uint2 ww;
        ww.x = cvtpk_bf16(v0, v1);
        ww.y = cvtpk_bf16(v2, v3);
        *reinterpret_cast<uint2*>(Xr + d0) = ww;
      }
  }
}

// ---------------- Proj GEMM (verified r12): 64x64 tiles, 768 blocks ----------------
__global__ __launch_bounds__(256) void proj_gemm(const uint16_t* __restrict__ A,
                                                 const uint16_t* __restrict__ W,
                                                 const float* __restrict__ bias,
                                                 float* __restrict__ out) {
  __shared__ __align__(16) uint16_t As[64 * 64];
  __shared__ __align__(16) uint16_t Bs[64 * 64];
  const int t    = threadIdx.x;
  const int lane = t & 63;
  const int wv   = t >> 6;
  const int wr   = wv >> 1, wc = wv & 1;
  const int bm   = blockIdx.x & 63;          // 64 M tiles
  const int bn   = blockIdx.x >> 6;          // 12 N tiles

  const uint16_t* Ag = A + (size_t)bm * 64 * 768;
  const uint16_t* Wg = W + (size_t)bn * 64 * 768;

  f32x4 zf = {0.f, 0.f, 0.f, 0.f};
  f32x4 acc[2][2];
#pragma unroll
  for (int m = 0; m < 2; m++)
#pragma unroll
    for (int n = 0; n < 2; n++) acc[m][n] = zf;

  for (int k0 = 0; k0 < 768; k0 += 64) {
#pragma unroll
    for (int j = 0; j < 2; j++) {
      int p = j * 256 + t;                   // chunk 0..511
      int r = p >> 3, x = p & 7;
      int scol = (x ^ (r & 7)) << 3;
      gload16(&As[p * 8], Ag + (size_t)r * 768 + k0 + scol);
      gload16(&Bs[p * 8], Wg + (size_t)r * 768 + k0 + scol);
    }
    __syncthreads();
#pragma unroll
    for (int kk = 0; kk < 2; kk++) {
      const int kc = kk * 32 + (lane >> 4) * 8;
      bf16x8 af[2], bf[2];
#pragma unroll
      for (int m = 0; m < 2; m++)
        af[m] = *reinterpret_cast<const bf16x8*>(&As[swz64((wr * 32 + m * 16 + (lane & 15)) * 64 + kc)]);
#pragma unroll
      for (int n = 0; n < 2; n++)
        bf[n] = *reinterpret_cast<const bf16x8*>(&Bs[swz64((wc * 32 + n * 16 + (lane & 15)) * 64 + kc)]);
#pragma unroll
      for (int m = 0; m < 2; m++)
#pragma unroll
        for (int n = 0; n < 2; n++)
          acc[m][n] = __builtin_amdgcn_mfma_f32_16x16x32_bf16(af[m], bf[n], acc[m][n], 0, 0, 0);
    }
    __syncthreads();
  }

#pragma unroll
  for (int n = 0; n < 2; n++) {
    const int f = bn * 64 + wc * 32 + n * 16 + (lane & 15);
    const float bv = bias[f];
#pragma unroll
    for (int m = 0; m < 2; m++)
#pragma unroll
      for (int r = 0; r < 4; r++) {
        int i = bm * 64 + wr * 32 + m * 16 + (lane >> 4) * 4 + r;
        out[(size_t)i * 768 + f] = acc[m][n][r] + bv;
      }
  }
}

extern "C" void kernel_launch(void* const* d_in, const int* in_sizes, int n_in,
                              void* d_out, int out_size, void* d_ws, size_t ws_size,
                              hipStream_t stream) {
  const float* inputs = (const float*)d_in[0];
  const int*   mask   = (const int*)d_in[1];
  const float* w_qkv  = (const float*)d_in[2];
  const float* b_qkv  = (const float*)d_in[3];
  const float* w_proj = (const float*)d_in[4];
  const float* b_proj = (const float*)d_in[5];
  float* out = (float*)d_out;

  uint16_t* a_bf  = (uint16_t*)d_ws;                    // 4096*768
  uint16_t* wq_bf = a_bf  + (size_t)4096 * 768;         // 2304*768
  uint16_t* wp_bf = wq_bf + (size_t)2304 * 768;         // 768*768
  uint16_t* q_bf  = wp_bf + (size_t)768 * 768;          // 24*2048*64
  uint16_t* k_bf  = q_bf  + (size_t)24 * 2048 * 64;     // compacted keys
  uint16_t* v_bf  = k_bf  + (size_t)24 * 2048 * 64;     // compacted, [B,H,D,Sc]
  uint16_t* x_bf  = v_bf  + (size_t)24 * 2048 * 64;     // 4096*768
  int*      cpos  = (int*)(x_bf + (size_t)4096 * 768);  // 2*2048 ints
  float*    mbc   = (float*)(cpos + 2 * 2048);          // 2*2048 floats
  int*      ntp   = (int*)(mbc + 2 * 2048);             // 2 ints

  const int n0 = 4096 * 768 / 4, n1 = 2304 * 768 / 4, n2 = 768 * 768 / 4;
  cvt_all<<<(n0 + n1 + n2 + 255) / 256, 256, 0, stream>>>(
      (const float4*)inputs, (ushort4*)a_bf, n0,
      (const float4*)w_qkv,  (ushort4*)wq_bf, n1,
      (const float4*)w_proj, (ushort4*)wp_bf, n2);
  mask_scan<<<2, 256, 0, stream>>>(mask, cpos, mbc, ntp, k_bf, v_bf);
  qkv_gemm<<<32 * 36, 256, 0, stream>>>(a_bf, wq_bf, b_qkv, cpos, q_bf, k_bf, v_bf);
  attn_kernel<<<24 * 32, 256, 0, stream>>>(q_bf, k_bf, v_bf, mbc, ntp, x_bf);
  proj_gemm<<<64 * 12, 256, 0, stream>>>(x_bf, wp_bf, b_proj, out);
}

// Round 16
// 84.362 us; speedup vs baseline: 1.3894x; 1.2823x over previous
//
#include <hip/hip_runtime.h>
#include <stdint.h>

#define S_LEN 2048
#define EMB   768
#define NHEAD 12
#define HDIM  64

typedef __attribute__((ext_vector_type(8)))  __bf16       bf16x8;
typedef __attribute__((ext_vector_type(4)))  float        f32x4;
typedef __attribute__((ext_vector_type(16))) float        f32x16;
typedef __attribute__((ext_vector_type(2)))  unsigned int u32x2;
typedef __attribute__((ext_vector_type(4)))  unsigned int u32x4;

__device__ __forceinline__ uint16_t f32_to_bf16(float f) {
  uint32_t u = __float_as_uint(f);
  u += 0x7FFFu + ((u >> 16) & 1u);           // round-to-nearest-even
  return (uint16_t)(u >> 16);
}

__device__ __forceinline__ uint32_t cvtpk_bf16(float lo, float hi) {
  uint32_t r;
  asm("v_cvt_pk_bf16_f32 %0, %1, %2" : "=v"(r) : "v"(lo), "v"(hi));
  return r;
}

#if __has_builtin(__builtin_amdgcn_exp2f)
#define EXP2F(x) __builtin_amdgcn_exp2f(x)
#else
#define EXP2F(x) exp2f(x)
#endif

#define ZERO16 {0.f,0.f,0.f,0.f,0.f,0.f,0.f,0.f,0.f,0.f,0.f,0.f,0.f,0.f,0.f,0.f}

// XOR swizzle for [rows][64] bf16 LDS tiles (idx in ushort units).
__device__ __forceinline__ int swz64(int idx) {
  return idx ^ (((idx >> 6) & 7) << 3);
}

// async global->LDS, 16B per lane; dest must be linear (wave base + lane*16)
__device__ __forceinline__ void gload16(uint16_t* lds, const uint16_t* g) {
  __builtin_amdgcn_global_load_lds((const __attribute__((address_space(1))) void*)g,
                                   (__attribute__((address_space(3))) void*)lds, 16, 0, 0);
}

// ---------------- fused fp32 -> bf16 convert (verified r12) ----------------
__global__ __launch_bounds__(256) void cvt_all(const float4* __restrict__ i0, ushort4* __restrict__ o0, int n0,
                                               const float4* __restrict__ i1, ushort4* __restrict__ o1, int n1,
                                               const float4* __restrict__ i2, ushort4* __restrict__ o2, int n2) {
  int gid = blockIdx.x * blockDim.x + threadIdx.x;
  const float4* src;
  ushort4* dst;
  int idx;
  if (gid < n0)           { src = i0; dst = o0; idx = gid; }
  else if (gid < n0 + n1) { src = i1; dst = o1; idx = gid - n0; }
  else if (gid < n0 + n1 + n2) { src = i2; dst = o2; idx = gid - n0 - n1; }
  else return;
  float4 v = src[idx];
  ushort4 o;
  o.x = f32_to_bf16(v.x); o.y = f32_to_bf16(v.y);
  o.z = f32_to_bf16(v.z); o.w = f32_to_bf16(v.w);
  dst[idx] = o;
}

// ---------------- mask scan (parallel): cpos, compact bias, tile counts ----------------
__global__ __launch_bounds__(256) void mask_scan(const int* __restrict__ mask,
                                                 int* __restrict__ cpos,
                                                 float* __restrict__ mbc,
                                                 int* __restrict__ ntp,
                                                 int* __restrict__ nbp) {
  const int b    = blockIdx.x;
  const int t    = threadIdx.x;
  const int lane = t & 63;
  const int wvi  = t >> 6;
  __shared__ int wsum[4];
  int m[8], u = 0;
#pragma unroll
  for (int j = 0; j < 8; j++) {
    m[j] = mask[b * S_LEN + t * 8 + j];
    u += (m[j] == 0);
  }
  // wave-level inclusive scan of u
  int x = u;
#pragma unroll
  for (int off = 1; off < 64; off <<= 1) {
    int v = __shfl_up(x, off);
    if (lane >= off) x += v;
  }
  if (lane == 63) wsum[wvi] = x;
  __syncthreads();
  int wbase = 0;
#pragma unroll
  for (int i = 0; i < 4; i++) wbase += (i < wvi) ? wsum[i] : 0;
  const int nb = wsum[0] + wsum[1] + wsum[2] + wsum[3];
  int base = wbase + x - u;                 // exclusive prefix for this thread
#pragma unroll
  for (int j = 0; j < 8; j++) {
    int sc = (m[j] == 0) ? base : -1;
    if (m[j] == 0) base++;
    cpos[b * S_LEN + t * 8 + j] = sc;
    mbc[b * S_LEN + t * 8 + j] = ((t * 8 + j) < nb) ? 0.0f : -1e30f;
  }
  if (t == 0) {
    ntp[b] = ((nb + 63) & ~63) >> 6;
    nbp[b] = nb;
  }
}

// ---------------- pad fill: zero the <=63 pad rows of K / pad cols of V^T ----------------
__global__ __launch_bounds__(256) void pad_fill(const int* __restrict__ nbp,
                                                uint16_t* __restrict__ kb,
                                                uint16_t* __restrict__ vb) {
  const int b = blockIdx.x / NHEAD, h = blockIdx.x % NHEAD;
  const int t = threadIdx.x;
  const int nb = nbp[b];
  const int padN = (nb + 63) & ~63;
  const int npad = padN - nb;
  for (int idx = t; idx < npad * HDIM; idx += 256) {
    int row = idx >> 6, d = idx & (HDIM - 1);
    kb[(((size_t)b * NHEAD + h) * S_LEN + nb + row) * HDIM + d] = 0;
    vb[(((size_t)b * NHEAD + h) * HDIM + d) * S_LEN + nb + row] = 0;
  }
}

// ---------------- QKV GEMM (verified r12 loop): BM=128, BN=64, 1152 blocks ----------------
// Epilogue specialized by block-uniform c = bn/12 (each 64-col tile is all-Q/K/V);
// K/V compact-scatter through cpos hoisted to 16 loads per thread.
__global__ __launch_bounds__(256) void qkv_gemm(const uint16_t* __restrict__ A,
                                                const uint16_t* __restrict__ W,
                                                const float* __restrict__ bias,
                                                const int* __restrict__ cpos,
                                                uint16_t* __restrict__ qb,
                                                uint16_t* __restrict__ kb,
                                                uint16_t* __restrict__ vb) {
  __shared__ __align__(16) uint16_t As[128 * 64];
  __shared__ __align__(16) uint16_t Bs[64 * 64];
  const int t    = threadIdx.x;
  const int lane = t & 63;
  const int wv   = t >> 6;
  const int wr   = wv >> 1, wc = wv & 1;
  // bijective XCD swizzle: 1152 = 8 * 144
  const int wg   = (blockIdx.x & 7) * 144 + (blockIdx.x >> 3);
  const int bm   = wg & 31;                  // 32 M tiles (128 rows)
  const int bn   = wg >> 5;                  // 36 N tiles (64 cols)

  const uint16_t* Ag = A + (size_t)bm * 128 * 768;
  const uint16_t* Wg = W + (size_t)bn * 64 * 768;

  f32x4 zf = {0.f, 0.f, 0.f, 0.f};
  f32x4 acc[4][2];
#pragma unroll
  for (int m = 0; m < 4; m++)
#pragma unroll
    for (int n = 0; n < 2; n++) acc[m][n] = zf;

  for (int k0 = 0; k0 < 768; k0 += 64) {
#pragma unroll
    for (int j = 0; j < 4; j++) {            // A tile: 1024 chunks
      int p = j * 256 + t;
      int r = p >> 3, x = p & 7;
      int scol = (x ^ (r & 7)) << 3;
      gload16(&As[p * 8], Ag + (size_t)r * 768 + k0 + scol);
    }
#pragma unroll
    for (int j = 0; j < 2; j++) {            // B tile: 512 chunks
      int p = j * 256 + t;
      int r = p >> 3, x = p & 7;
      int scol = (x ^ (r & 7)) << 3;
      gload16(&Bs[p * 8], Wg + (size_t)r * 768 + k0 + scol);
    }
    __syncthreads();
#pragma unroll
    for (int kk = 0; kk < 2; kk++) {
      const int kc = kk * 32 + (lane >> 4) * 8;
      bf16x8 af[4], bf[2];
#pragma unroll
      for (int m = 0; m < 4; m++)
        af[m] = *reinterpret_cast<const bf16x8*>(&As[swz64((wr * 64 + m * 16 + (lane & 15)) * 64 + kc)]);
#pragma unroll
      for (int n = 0; n < 2; n++)
        bf[n] = *reinterpret_cast<const bf16x8*>(&Bs[swz64((wc * 32 + n * 16 + (lane & 15)) * 64 + kc)]);
#pragma unroll
      for (int m = 0; m < 4; m++)
#pragma unroll
        for (int n = 0; n < 2; n++)
          acc[m][n] = __builtin_amdgcn_mfma_f32_16x16x32_bf16(af[m], bf[n], acc[m][n], 0, 0, 0);
    }
    __syncthreads();
  }

  const int cQ = bn / 12;                    // 0=Q, 1=K, 2=V (block-uniform)
  int scv[4][4];
  if (cQ != 0) {
#pragma unroll
    for (int m = 0; m < 4; m++)
#pragma unroll
      for (int r = 0; r < 4; r++) {
        int i = bm * 128 + wr * 64 + m * 16 + (lane >> 4) * 4 + r;
        scv[m][r] = cpos[(i >> 11) * S_LEN + (i & 2047)];
      }
  }
#pragma unroll
  for (int n = 0; n < 2; n++) {
    const int f   = bn * 64 + wc * 32 + n * 16 + (lane & 15);
    const float bv = bias[f];
    const int rem = f - cQ * 768;
    const int h   = rem >> 6, d = rem & 63;
    const float scl = (cQ == 0) ? 0.125f * 1.44269504f : 1.0f;  // SCALE*log2e folded into Q
#pragma unroll
    for (int m = 0; m < 4; m++) {
#pragma unroll
      for (int r = 0; r < 4; r++) {
        int i = bm * 128 + wr * 64 + m * 16 + (lane >> 4) * 4 + r;
        int b = i >> 11, s = i & 2047;
        uint16_t val = f32_to_bf16((acc[m][n][r] + bv) * scl);
        if (cQ == 0) {
          qb[(((size_t)b * NHEAD + h) * S_LEN + s) * HDIM + d] = val;
        } else {
          int sc = scv[m][r];
          if (sc >= 0) {
            if (cQ == 1)
              kb[(((size_t)b * NHEAD + h) * S_LEN + sc) * HDIM + d] = val;
            else
              vb[(((size_t)b * NHEAD + h) * HDIM + d) * S_LEN + sc] = val;  // V transposed
          }
        }
      }
    }
  }
}

// ---------------- Flash attention (r15 body): compacted keys, tail-only bias ----------------
__global__ __launch_bounds__(256, 3) void attn_kernel(const uint16_t* __restrict__ Q,   // [BH][S][D], pre-scaled
                                                      const uint16_t* __restrict__ Kb,  // [BH][Sc][D] compacted
                                                      const uint16_t* __restrict__ Vb,  // [BH][D][Sc] compacted
                                                      const float* __restrict__ mbc,    // [B][S] compact bias
                                                      const int* __restrict__ ntp,      // [B] tile count
                                                      uint16_t* __restrict__ X) {       // [B][S][E] bf16
  __shared__ __align__(16) uint16_t Kd[2][64 * 64];
  __shared__ __align__(16) uint16_t Vd[2][64 * 64];   // [d][key]
  __shared__ __align__(16) float    mb_s[S_LEN];
  __shared__ float Lc[2][32];

  const int t    = threadIdx.x;
  const int lane = t & 63;
  const int hl   = lane >> 5;                   // lane half
  const int q31  = lane & 31;
  const int wv   = t >> 6;
  const int qg   = wv & 1;                      // q-group
  const int kh   = wv >> 1;                     // key-half
  // bijective XCD swizzle: 768 = 8 * 96; each XCD gets 3 whole heads (L2-fit K/V)
  const int wg   = (blockIdx.x & 7) * 96 + (blockIdx.x >> 3);
  const int qblk = wg & 31;
  const int bh   = wg >> 5;
  const int b    = bh / NHEAD, hd = bh % NHEAD;

  const uint16_t* Qh = Q  + (size_t)bh * S_LEN * HDIM;
  const uint16_t* Kh = Kb + (size_t)bh * S_LEN * HDIM;
  const uint16_t* Vh = Vb + (size_t)bh * HDIM * S_LEN;
  const int q0 = qblk * 64 + qg * 32;
  const int nt = ntp[b];

  // compact bias preload (8 keys/thread, coalesced float4)
  {
    float4 f0 = *reinterpret_cast<const float4*>(&mbc[b * S_LEN + t * 8]);
    float4 f1 = *reinterpret_cast<const float4*>(&mbc[b * S_LEN + t * 8 + 4]);
    *reinterpret_cast<float4*>(&mb_s[t * 8])     = f0;
    *reinterpret_cast<float4*>(&mb_s[t * 8 + 4]) = f1;
  }

  // Q as B-fragments: col=q31, k=d=16s+8hl+j
  bf16x8 qf[4];
#pragma unroll
  for (int s = 0; s < 4; s++)
    qf[s] = *reinterpret_cast<const bf16x8*>(Qh + (size_t)(q0 + q31) * HDIM + 16 * s + 8 * hl);

  f32x16 oacc[2] = {ZERO16, ZERO16};
  float lsum = 0.f;

  const uint16_t* kga[2]; const uint16_t* vga[2]; int lof[2];
#pragma unroll
  for (int j = 0; j < 2; j++) {
    int p = j * 256 + t, r = p >> 3, x = p & 7;
    int scol = (x ^ (r & 7)) << 3;
    kga[j] = Kh + (size_t)r * HDIM + scol;
    vga[j] = Vh + (size_t)r * S_LEN + scol;
    lof[j] = p * 8;
  }
  auto stage = [&](int nb2, int it2) {   // 4 vmem instructions per thread
#pragma unroll
    for (int j = 0; j < 2; j++) {
      gload16(&Kd[nb2][lof[j]], kga[j] + it2 * 64 * HDIM);
      gload16(&Vd[nb2][lof[j]], vga[j] + it2 * 64);
    }
  };

  stage(0, 0);
  __syncthreads();                       // prologue: full drain, bias + buf0 ready

#pragma unroll 2
  for (int it = 0; it < nt; ++it) {
    const int cur = it & 1;
    __builtin_amdgcn_s_barrier();        // A: all waves done compute(it-1) -> buf cur^1 free
    __builtin_amdgcn_sched_barrier(0);
    if (it + 1 < nt) {
      stage(cur ^ 1, it + 1);            // next-tile loads: stay in flight across B
      asm volatile("s_waitcnt vmcnt(4)" ::: "memory");   // my tile-it loads done
    } else {
      asm volatile("s_waitcnt vmcnt(0)" ::: "memory");
    }
    __builtin_amdgcn_s_barrier();        // B: buf cur staged block-wide
    __builtin_amdgcn_sched_barrier(0);

    // QK^T (swapped): scc[reg] = S[key_loc=(reg&3)+8*(reg>>2)+4*hl][q31]
    f32x16 scc = ZERO16;
    __builtin_amdgcn_s_setprio(1);
#pragma unroll
    for (int s = 0; s < 4; s++) {
      bf16x8 kf = *reinterpret_cast<const bf16x8*>(&Kd[cur][swz64((kh * 32 + q31) * 64 + 16 * s + 8 * hl)]);
      scc = __builtin_amdgcn_mfma_f32_32x32x16_bf16(kf, qf[s], scc, 0, 0, 0);
    }
    __builtin_amdgcn_s_setprio(0);

    // exp2 + per-lane sum; bias only on the tail tile (compacted keys have bias 0)
    uint32_t w[4][2];
    if (it == nt - 1) {
#pragma unroll
      for (int s2 = 0; s2 < 4; s2++) {
        f32x4 mbv = *reinterpret_cast<const f32x4*>(&mb_s[it * 64 + kh * 32 + s2 * 8 + hl * 4]);
        float p0 = EXP2F(scc[4 * s2 + 0] + mbv[0]);
        float p1 = EXP2F(scc[4 * s2 + 1] + mbv[1]);
        float p2 = EXP2F(scc[4 * s2 + 2] + mbv[2]);
        float p3 = EXP2F(scc[4 * s2 + 3] + mbv[3]);
        lsum += (p0 + p1) + (p2 + p3);
        w[s2][0] = cvtpk_bf16(p0, p1);
        w[s2][1] = cvtpk_bf16(p2, p3);
      }
    } else {
#pragma unroll
      for (int s2 = 0; s2 < 4; s2++) {
        float p0 = EXP2F(scc[4 * s2 + 0]);
        float p1 = EXP2F(scc[4 * s2 + 1]);
        float p2 = EXP2F(scc[4 * s2 + 2]);
        float p3 = EXP2F(scc[4 * s2 + 3]);
        lsum += (p0 + p1) + (p2 + p3);
        w[s2][0] = cvtpk_bf16(p0, p1);
        w[s2][1] = cvtpk_bf16(p2, p3);
      }
    }

    // redistribute P into PV B-fragments: pb[ks][j] = P[16ks+8hl+j][q31]
    bf16x8 pb[2];
#pragma unroll
    for (int ks = 0; ks < 2; ks++) {
      u32x2 r0 = __builtin_amdgcn_permlane32_swap(w[2 * ks][0], w[2 * ks + 1][0], false, false);
      u32x2 r1 = __builtin_amdgcn_permlane32_swap(w[2 * ks][1], w[2 * ks + 1][1], false, false);
      u32x4 uu;
      uu.x = r0.x; uu.y = r1.x; uu.z = r0.y; uu.w = r1.y;
      pb[ks] = __builtin_bit_cast(bf16x8, uu);
    }

    // PV (swapped): O^T[d][q] += V^T[d][k] * P[k][q]
    __builtin_amdgcn_s_setprio(1);
#pragma unroll
    for (int mt = 0; mt < 2; mt++)
#pragma unroll
      for (int ks = 0; ks < 2; ks++) {
        bf16x8 vf = *reinterpret_cast<const bf16x8*>(&Vd[cur][swz64((mt * 32 + q31) * 64 + kh * 32 + ks * 16 + hl * 8)]);
        oacc[mt] = __builtin_amdgcn_mfma_f32_32x32x16_bf16(vf, pb[ks], oacc[mt], 0, 0, 0);
      }
    __builtin_amdgcn_s_setprio(0);
  }

  // per-wave row sum for column q31
  lsum += __shfl_xor(lsum, 32);

  __syncthreads();   // nt may be odd: all waves done reading buf0 before Oc alias write

  // combine key-half partials: kh=1 writes O^T and l, kh=0 finishes
  float* Oc = qg ? (float*)&Vd[0][0] : (float*)&Kd[0][0];   // [64 d][32 q]
  if (kh == 1) {
#pragma unroll
    for (int mt = 0; mt < 2; mt++)
#pragma unroll
      for (int e = 0; e < 16; e++) {
        int d = mt * 32 + (e & 3) + (e >> 2) * 8 + hl * 4;
        Oc[d * 32 + q31] = oacc[mt][e];
      }
    if (hl == 0) Lc[qg][q31] = lsum;
  }
  __syncthreads();
  if (kh == 0) {
    float linv = 1.0f / (lsum + Lc[qg][q31]);
    uint16_t* Xr = X + ((size_t)b * S_LEN + q0 + q31) * EMB + hd * HDIM;
#pragma unroll
    for (int mt = 0; mt < 2; mt++)
#pragma unroll
      for (int s2 = 0; s2 < 4; s2++) {
        int d0 = mt * 32 + s2 * 8 + hl * 4;
        float v0 = (oacc[mt][4 * s2 + 0] + Oc[(d0 + 0) * 32 + q31]) * linv;
        float v1 = (oacc[mt][4 * s2 + 1] + Oc[(d0 + 1) * 32 + q31]) * linv;
        float v2 = (oacc[mt][4 * s2 + 2] + Oc[(d0 + 2) * 32 + q31]) * linv;
        float v3 = (oacc[mt][4 * s2 + 3] + Oc[(d0 + 3) * 32 + q31]) * linv;
        uint2 ww;
        ww.x = cvtpk_bf16(v0, v1);
        ww.y = cvtpk_bf16(v2, v3);
        *reinterpret_cast<uint2*>(Xr + d0) = ww;
      }
  }
}

// ---------------- Proj GEMM (verified r12): 64x64 tiles, 768 blocks ----------------
__global__ __launch_bounds__(256) void proj_gemm(const uint16_t* __restrict__ A,
                                                 const uint16_t* __restrict__ W,
                                                 const float* __restrict__ bias,
                                                 float* __restrict__ out) {
  __shared__ __align__(16) uint16_t As[64 * 64];
  __shared__ __align__(16) uint16_t Bs[64 * 64];
  const int t    = threadIdx.x;
  const int lane = t & 63;
  const int wv   = t >> 6;
  const int wr   = wv >> 1, wc = wv & 1;
  const int bm   = blockIdx.x & 63;          // 64 M tiles
  const int bn   = blockIdx.x >> 6;          // 12 N tiles

  const uint16_t* Ag = A + (size_t)bm * 64 * 768;
  const uint16_t* Wg = W + (size_t)bn * 64 * 768;

  f32x4 zf = {0.f, 0.f, 0.f, 0.f};
  f32x4 acc[2][2];
#pragma unroll
  for (int m = 0; m < 2; m++)
#pragma unroll
    for (int n = 0; n < 2; n++) acc[m][n] = zf;

  for (int k0 = 0; k0 < 768; k0 += 64) {
#pragma unroll
    for (int j = 0; j < 2; j++) {
      int p = j * 256 + t;                   // chunk 0..511
      int r = p >> 3, x = p & 7;
      int scol = (x ^ (r & 7)) << 3;
      gload16(&As[p * 8], Ag + (size_t)r * 768 + k0 + scol);
      gload16(&Bs[p * 8], Wg + (size_t)r * 768 + k0 + scol);
    }
    __syncthreads();
#pragma unroll
    for (int kk = 0; kk < 2; kk++) {
      const int kc = kk * 32 + (lane >> 4) * 8;
      bf16x8 af[2], bf[2];
#pragma unroll
      for (int m = 0; m < 2; m++)
        af[m] = *reinterpret_cast<const bf16x8*>(&As[swz64((wr * 32 + m * 16 + (lane & 15)) * 64 + kc)]);
#pragma unroll
      for (int n = 0; n < 2; n++)
        bf[n] = *reinterpret_cast<const bf16x8*>(&Bs[swz64((wc * 32 + n * 16 + (lane & 15)) * 64 + kc)]);
#pragma unroll
      for (int m = 0; m < 2; m++)
#pragma unroll
        for (int n = 0; n < 2; n++)
          acc[m][n] = __builtin_amdgcn_mfma_f32_16x16x32_bf16(af[m], bf[n], acc[m][n], 0, 0, 0);
    }
    __syncthreads();
  }

#pragma unroll
  for (int n = 0; n < 2; n++) {
    const int f = bn * 64 + wc * 32 + n * 16 + (lane & 15);
    const float bv = bias[f];
#pragma unroll
    for (int m = 0; m < 2; m++)
#pragma unroll
      for (int r = 0; r < 4; r++) {
        int i = bm * 64 + wr * 32 + m * 16 + (lane >> 4) * 4 + r;
        out[(size_t)i * 768 + f] = acc[m][n][r] + bv;
      }
  }
}

extern "C" void kernel_launch(void* const* d_in, const int* in_sizes, int n_in,
                              void* d_out, int out_size, void* d_ws, size_t ws_size,
                              hipStream_t stream) {
  const float* inputs = (const float*)d_in[0];
  const int*   mask   = (const int*)d_in[1];
  const float* w_qkv  = (const float*)d_in[2];
  const float* b_qkv  = (const float*)d_in[3];
  const float* w_proj = (const float*)d_in[4];
  const float* b_proj = (const float*)d_in[5];
  float* out = (float*)d_out;

  uint16_t* a_bf  = (uint16_t*)d_ws;                    // 4096*768
  uint16_t* wq_bf = a_bf  + (size_t)4096 * 768;         // 2304*768
  uint16_t* wp_bf = wq_bf + (size_t)2304 * 768;         // 768*768
  uint16_t* q_bf  = wp_bf + (size_t)768 * 768;          // 24*2048*64
  uint16_t* k_bf  = q_bf  + (size_t)24 * 2048 * 64;     // compacted keys
  uint16_t* v_bf  = k_bf  + (size_t)24 * 2048 * 64;     // compacted, [B,H,D,Sc]
  uint16_t* x_bf  = v_bf  + (size_t)24 * 2048 * 64;     // 4096*768
  int*      cpos  = (int*)(x_bf + (size_t)4096 * 768);  // 2*2048 ints
  float*    mbc   = (float*)(cpos + 2 * 2048);          // 2*2048 floats
  int*      ntp   = (int*)(mbc + 2 * 2048);             // 2 ints
  int*      nbp   = ntp + 2;                            // 2 ints

  const int n0 = 4096 * 768 / 4, n1 = 2304 * 768 / 4, n2 = 768 * 768 / 4;
  cvt_all<<<(n0 + n1 + n2 + 255) / 256, 256, 0, stream>>>(
      (const float4*)inputs, (ushort4*)a_bf, n0,
      (const float4*)w_qkv,  (ushort4*)wq_bf, n1,
      (const float4*)w_proj, (ushort4*)wp_bf, n2);
  mask_scan<<<2, 256, 0, stream>>>(mask, cpos, mbc, ntp, nbp);
  pad_fill<<<2 * NHEAD, 256, 0, stream>>>(nbp, k_bf, v_bf);
  qkv_gemm<<<32 * 36, 256, 0, stream>>>(a_bf, wq_bf, b_qkv, cpos, q_bf, k_bf, v_bf);
  attn_kernel<<<24 * 32, 256, 0, stream>>>(q_bf, k_bf, v_bf, mbc, ntp, x_bf);
  proj_gemm<<<64 * 12, 256, 0, stream>>>(x_bf, wp_bf, b_proj, out);
}

// Round 17
// 83.114 us; speedup vs baseline: 1.4102x; 1.0150x over previous
//
#include <hip/hip_runtime.h>
#include <stdint.h>

#define S_LEN 2048
#define EMB   768
#define NHEAD 12
#define HDIM  64

typedef __attribute__((ext_vector_type(8)))  __bf16       bf16x8;
typedef __attribute__((ext_vector_type(4)))  float        f32x4;
typedef __attribute__((ext_vector_type(16))) float        f32x16;
typedef __attribute__((ext_vector_type(2)))  unsigned int u32x2;
typedef __attribute__((ext_vector_type(4)))  unsigned int u32x4;

__device__ __forceinline__ uint16_t f32_to_bf16(float f) {
  uint32_t u = __float_as_uint(f);
  u += 0x7FFFu + ((u >> 16) & 1u);           // round-to-nearest-even
  return (uint16_t)(u >> 16);
}

__device__ __forceinline__ uint32_t cvtpk_bf16(float lo, float hi) {
  uint32_t r;
  asm("v_cvt_pk_bf16_f32 %0, %1, %2" : "=v"(r) : "v"(lo), "v"(hi));
  return r;
}

#if __has_builtin(__builtin_amdgcn_exp2f)
#define EXP2F(x) __builtin_amdgcn_exp2f(x)
#else
#define EXP2F(x) exp2f(x)
#endif

#define ZERO16 {0.f,0.f,0.f,0.f,0.f,0.f,0.f,0.f,0.f,0.f,0.f,0.f,0.f,0.f,0.f,0.f}

// XOR swizzle for [rows][64] bf16 LDS tiles (idx in ushort units).
__device__ __forceinline__ int swz64(int idx) {
  return idx ^ (((idx >> 6) & 7) << 3);
}

// async global->LDS, 16B per lane; dest must be linear (wave base + lane*16)
__device__ __forceinline__ void gload16(uint16_t* lds, const uint16_t* g) {
  __builtin_amdgcn_global_load_lds((const __attribute__((address_space(1))) void*)g,
                                   (__attribute__((address_space(3))) void*)lds, 16, 0, 0);
}

// ---------------- fused fp32 -> bf16 convert (verified r12) ----------------
__global__ __launch_bounds__(256) void cvt_all(const float4* __restrict__ i0, ushort4* __restrict__ o0, int n0,
                                               const float4* __restrict__ i1, ushort4* __restrict__ o1, int n1,
                                               const float4* __restrict__ i2, ushort4* __restrict__ o2, int n2) {
  int gid = blockIdx.x * blockDim.x + threadIdx.x;
  const float4* src;
  ushort4* dst;
  int idx;
  if (gid < n0)           { src = i0; dst = o0; idx = gid; }
  else if (gid < n0 + n1) { src = i1; dst = o1; idx = gid - n0; }
  else if (gid < n0 + n1 + n2) { src = i2; dst = o2; idx = gid - n0 - n1; }
  else return;
  float4 v = src[idx];
  ushort4 o;
  o.x = f32_to_bf16(v.x); o.y = f32_to_bf16(v.y);
  o.z = f32_to_bf16(v.z); o.w = f32_to_bf16(v.w);
  dst[idx] = o;
}

// ---------------- mask scan (parallel): cpos, compact bias, tile counts ----------------
__global__ __launch_bounds__(256) void mask_scan(const int* __restrict__ mask,
                                                 int* __restrict__ cpos,
                                                 float* __restrict__ mbc,
                                                 int* __restrict__ ntp,
                                                 int* __restrict__ nbp) {
  const int b    = blockIdx.x;
  const int t    = threadIdx.x;
  const int lane = t & 63;
  const int wvi  = t >> 6;
  __shared__ int wsum[4];
  int m[8], u = 0;
#pragma unroll
  for (int j = 0; j < 8; j++) {
    m[j] = mask[b * S_LEN + t * 8 + j];
    u += (m[j] == 0);
  }
  // wave-level inclusive scan of u
  int x = u;
#pragma unroll
  for (int off = 1; off < 64; off <<= 1) {
    int v = __shfl_up(x, off);
    if (lane >= off) x += v;
  }
  if (lane == 63) wsum[wvi] = x;
  __syncthreads();
  int wbase = 0;
#pragma unroll
  for (int i = 0; i < 4; i++) wbase += (i < wvi) ? wsum[i] : 0;
  const int nb = wsum[0] + wsum[1] + wsum[2] + wsum[3];
  int base = wbase + x - u;                 // exclusive prefix for this thread
#pragma unroll
  for (int j = 0; j < 8; j++) {
    int sc = (m[j] == 0) ? base : -1;
    if (m[j] == 0) base++;
    cpos[b * S_LEN + t * 8 + j] = sc;
    mbc[b * S_LEN + t * 8 + j] = ((t * 8 + j) < nb) ? 0.0f : -1e30f;
  }
  if (t == 0) {
    ntp[b] = ((nb + 63) & ~63) >> 6;
    nbp[b] = nb;
  }
}

// ---------------- pad fill: zero the <=63 pad rows of K / pad cols of V^T ----------------
__global__ __launch_bounds__(256) void pad_fill(const int* __restrict__ nbp,
                                                uint16_t* __restrict__ kb,
                                                uint16_t* __restrict__ vb) {
  const int b = blockIdx.x / NHEAD, h = blockIdx.x % NHEAD;
  const int t = threadIdx.x;
  const int nb = nbp[b];
  const int padN = (nb + 63) & ~63;
  const int npad = padN - nb;
  for (int idx = t; idx < npad * HDIM; idx += 256) {
    int row = idx >> 6, d = idx & (HDIM - 1);
    kb[(((size_t)b * NHEAD + h) * S_LEN + nb + row) * HDIM + d] = 0;
    vb[(((size_t)b * NHEAD + h) * HDIM + d) * S_LEN + nb + row] = 0;
  }
}

// ---------------- QKV GEMM (verified r16 body): BM=128, BN=64, 1152 blocks ----------------
// NEW: bn-fast XCD-chunked decode. Each XCD owns 4 bm x all 36 bn -> per-XCD
// working set = 0.79MB A-chunk + 3.4MB W ~= 4MB L2, so A re-reads are L2 hits
// (was: bm-fast -> 6.3MB A streamed from L3 per XCD = the ~45us floor).
__global__ __launch_bounds__(256) void qkv_gemm(const uint16_t* __restrict__ A,
                                                const uint16_t* __restrict__ W,
                                                const float* __restrict__ bias,
                                                const int* __restrict__ cpos,
                                                uint16_t* __restrict__ qb,
                                                uint16_t* __restrict__ kb,
                                                uint16_t* __restrict__ vb) {
  __shared__ __align__(16) uint16_t As[128 * 64];
  __shared__ __align__(16) uint16_t Bs[64 * 64];
  const int t    = threadIdx.x;
  const int lane = t & 63;
  const int wv   = t >> 6;
  const int wr   = wv >> 1, wc = wv & 1;
  // bijective XCD swizzle, bn-fast: 1152 = 8 * 144, 144 = 4 bm * 36 bn
  const int wg   = (blockIdx.x & 7) * 144 + (blockIdx.x >> 3);
  const int bm   = wg / 36;                  // 32 M tiles (128 rows); 4 per XCD
  const int bn   = wg % 36;                  // 36 N tiles (64 cols); all per XCD

  const uint16_t* Ag = A + (size_t)bm * 128 * 768;
  const uint16_t* Wg = W + (size_t)bn * 64 * 768;

  f32x4 zf = {0.f, 0.f, 0.f, 0.f};
  f32x4 acc[4][2];
#pragma unroll
  for (int m = 0; m < 4; m++)
#pragma unroll
    for (int n = 0; n < 2; n++) acc[m][n] = zf;

  for (int k0 = 0; k0 < 768; k0 += 64) {
#pragma unroll
    for (int j = 0; j < 4; j++) {            // A tile: 1024 chunks
      int p = j * 256 + t;
      int r = p >> 3, x = p & 7;
      int scol = (x ^ (r & 7)) << 3;
      gload16(&As[p * 8], Ag + (size_t)r * 768 + k0 + scol);
    }
#pragma unroll
    for (int j = 0; j < 2; j++) {            // B tile: 512 chunks
      int p = j * 256 + t;
      int r = p >> 3, x = p & 7;
      int scol = (x ^ (r & 7)) << 3;
      gload16(&Bs[p * 8], Wg + (size_t)r * 768 + k0 + scol);
    }
    __syncthreads();
#pragma unroll
    for (int kk = 0; kk < 2; kk++) {
      const int kc = kk * 32 + (lane >> 4) * 8;
      bf16x8 af[4], bf[2];
#pragma unroll
      for (int m = 0; m < 4; m++)
        af[m] = *reinterpret_cast<const bf16x8*>(&As[swz64((wr * 64 + m * 16 + (lane & 15)) * 64 + kc)]);
#pragma unroll
      for (int n = 0; n < 2; n++)
        bf[n] = *reinterpret_cast<const bf16x8*>(&Bs[swz64((wc * 32 + n * 16 + (lane & 15)) * 64 + kc)]);
#pragma unroll
      for (int m = 0; m < 4; m++)
#pragma unroll
        for (int n = 0; n < 2; n++)
          acc[m][n] = __builtin_amdgcn_mfma_f32_16x16x32_bf16(af[m], bf[n], acc[m][n], 0, 0, 0);
    }
    __syncthreads();
  }

  const int cQ = bn / 12;                    // 0=Q, 1=K, 2=V (block-uniform)
  int scv[4][4];
  if (cQ != 0) {
#pragma unroll
    for (int m = 0; m < 4; m++)
#pragma unroll
      for (int r = 0; r < 4; r++) {
        int i = bm * 128 + wr * 64 + m * 16 + (lane >> 4) * 4 + r;
        scv[m][r] = cpos[(i >> 11) * S_LEN + (i & 2047)];
      }
  }
#pragma unroll
  for (int n = 0; n < 2; n++) {
    const int f   = bn * 64 + wc * 32 + n * 16 + (lane & 15);
    const float bv = bias[f];
    const int rem = f - cQ * 768;
    const int h   = rem >> 6, d = rem & 63;
    const float scl = (cQ == 0) ? 0.125f * 1.44269504f : 1.0f;  // SCALE*log2e folded into Q
#pragma unroll
    for (int m = 0; m < 4; m++) {
#pragma unroll
      for (int r = 0; r < 4; r++) {
        int i = bm * 128 + wr * 64 + m * 16 + (lane >> 4) * 4 + r;
        int b = i >> 11, s = i & 2047;
        uint16_t val = f32_to_bf16((acc[m][n][r] + bv) * scl);
        if (cQ == 0) {
          qb[(((size_t)b * NHEAD + h) * S_LEN + s) * HDIM + d] = val;
        } else {
          int sc = scv[m][r];
          if (sc >= 0) {
            if (cQ == 1)
              kb[(((size_t)b * NHEAD + h) * S_LEN + sc) * HDIM + d] = val;
            else
              vb[(((size_t)b * NHEAD + h) * HDIM + d) * S_LEN + sc] = val;  // V transposed
          }
        }
      }
    }
  }
}

// ---------------- Flash attention (verified r16): compacted keys, tail-only bias ----------------
__global__ __launch_bounds__(256, 3) void attn_kernel(const uint16_t* __restrict__ Q,   // [BH][S][D], pre-scaled
                                                      const uint16_t* __restrict__ Kb,  // [BH][Sc][D] compacted
                                                      const uint16_t* __restrict__ Vb,  // [BH][D][Sc] compacted
                                                      const float* __restrict__ mbc,    // [B][S] compact bias
                                                      const int* __restrict__ ntp,      // [B] tile count
                                                      uint16_t* __restrict__ X) {       // [B][S][E] bf16
  __shared__ __align__(16) uint16_t Kd[2][64 * 64];
  __shared__ __align__(16) uint16_t Vd[2][64 * 64];   // [d][key]
  __shared__ __align__(16) float    mb_s[S_LEN];
  __shared__ float Lc[2][32];

  const int t    = threadIdx.x;
  const int lane = t & 63;
  const int hl   = lane >> 5;                   // lane half
  const int q31  = lane & 31;
  const int wv   = t >> 6;
  const int qg   = wv & 1;                      // q-group
  const int kh   = wv >> 1;                     // key-half
  // bijective XCD swizzle: 768 = 8 * 96; each XCD gets 3 whole heads (L2-fit K/V)
  const int wg   = (blockIdx.x & 7) * 96 + (blockIdx.x >> 3);
  const int qblk = wg & 31;
  const int bh   = wg >> 5;
  const int b    = bh / NHEAD, hd = bh % NHEAD;

  const uint16_t* Qh = Q  + (size_t)bh * S_LEN * HDIM;
  const uint16_t* Kh = Kb + (size_t)bh * S_LEN * HDIM;
  const uint16_t* Vh = Vb + (size_t)bh * HDIM * S_LEN;
  const int q0 = qblk * 64 + qg * 32;
  const int nt = ntp[b];

  // compact bias preload (8 keys/thread, coalesced float4)
  {
    float4 f0 = *reinterpret_cast<const float4*>(&mbc[b * S_LEN + t * 8]);
    float4 f1 = *reinterpret_cast<const float4*>(&mbc[b * S_LEN + t * 8 + 4]);
    *reinterpret_cast<float4*>(&mb_s[t * 8])     = f0;
    *reinterpret_cast<float4*>(&mb_s[t * 8 + 4]) = f1;
  }

  // Q as B-fragments: col=q31, k=d=16s+8hl+j
  bf16x8 qf[4];
#pragma unroll
  for (int s = 0; s < 4; s++)
    qf[s] = *reinterpret_cast<const bf16x8*>(Qh + (size_t)(q0 + q31) * HDIM + 16 * s + 8 * hl);

  f32x16 oacc[2] = {ZERO16, ZERO16};
  float lsum = 0.f;

  const uint16_t* kga[2]; const uint16_t* vga[2]; int lof[2];
#pragma unroll
  for (int j = 0; j < 2; j++) {
    int p = j * 256 + t, r = p >> 3, x = p & 7;
    int scol = (x ^ (r & 7)) << 3;
    kga[j] = Kh + (size_t)r * HDIM + scol;
    vga[j] = Vh + (size_t)r * S_LEN + scol;
    lof[j] = p * 8;
  }
  auto stage = [&](int nb2, int it2) {   // 4 vmem instructions per thread
#pragma unroll
    for (int j = 0; j < 2; j++) {
      gload16(&Kd[nb2][lof[j]], kga[j] + it2 * 64 * HDIM);
      gload16(&Vd[nb2][lof[j]], vga[j] + it2 * 64);
    }
  };

  stage(0, 0);
  __syncthreads();                       // prologue: full drain, bias + buf0 ready

#pragma unroll 2
  for (int it = 0; it < nt; ++it) {
    const int cur = it & 1;
    __builtin_amdgcn_s_barrier();        // A: all waves done compute(it-1) -> buf cur^1 free
    __builtin_amdgcn_sched_barrier(0);
    if (it + 1 < nt) {
      stage(cur ^ 1, it + 1);            // next-tile loads: stay in flight across B
      asm volatile("s_waitcnt vmcnt(4)" ::: "memory");   // my tile-it loads done
    } else {
      asm volatile("s_waitcnt vmcnt(0)" ::: "memory");
    }
    __builtin_amdgcn_s_barrier();        // B: buf cur staged block-wide
    __builtin_amdgcn_sched_barrier(0);

    // QK^T (swapped): scc[reg] = S[key_loc=(reg&3)+8*(reg>>2)+4*hl][q31]
    f32x16 scc = ZERO16;
    __builtin_amdgcn_s_setprio(1);
#pragma unroll
    for (int s = 0; s < 4; s++) {
      bf16x8 kf = *reinterpret_cast<const bf16x8*>(&Kd[cur][swz64((kh * 32 + q31) * 64 + 16 * s + 8 * hl)]);
      scc = __builtin_amdgcn_mfma_f32_32x32x16_bf16(kf, qf[s], scc, 0, 0, 0);
    }
    __builtin_amdgcn_s_setprio(0);

    // exp2 + per-lane sum; bias only on the tail tile (compacted keys have bias 0)
    uint32_t w[4][2];
    if (it == nt - 1) {
#pragma unroll
      for (int s2 = 0; s2 < 4; s2++) {
        f32x4 mbv = *reinterpret_cast<const f32x4*>(&mb_s[it * 64 + kh * 32 + s2 * 8 + hl * 4]);
        float p0 = EXP2F(scc[4 * s2 + 0] + mbv[0]);
        float p1 = EXP2F(scc[4 * s2 + 1] + mbv[1]);
        float p2 = EXP2F(scc[4 * s2 + 2] + mbv[2]);
        float p3 = EXP2F(scc[4 * s2 + 3] + mbv[3]);
        lsum += (p0 + p1) + (p2 + p3);
        w[s2][0] = cvtpk_bf16(p0, p1);
        w[s2][1] = cvtpk_bf16(p2, p3);
      }
    } else {
#pragma unroll
      for (int s2 = 0; s2 < 4; s2++) {
        float p0 = EXP2F(scc[4 * s2 + 0]);
        float p1 = EXP2F(scc[4 * s2 + 1]);
        float p2 = EXP2F(scc[4 * s2 + 2]);
        float p3 = EXP2F(scc[4 * s2 + 3]);
        lsum += (p0 + p1) + (p2 + p3);
        w[s2][0] = cvtpk_bf16(p0, p1);
        w[s2][1] = cvtpk_bf16(p2, p3);
      }
    }

    // redistribute P into PV B-fragments: pb[ks][j] = P[16ks+8hl+j][q31]
    bf16x8 pb[2];
#pragma unroll
    for (int ks = 0; ks < 2; ks++) {
      u32x2 r0 = __builtin_amdgcn_permlane32_swap(w[2 * ks][0], w[2 * ks + 1][0], false, false);
      u32x2 r1 = __builtin_amdgcn_permlane32_swap(w[2 * ks][1], w[2 * ks + 1][1], false, false);
      u32x4 uu;
      uu.x = r0.x; uu.y = r1.x; uu.z = r0.y; uu.w = r1.y;
      pb[ks] = __builtin_bit_cast(bf16x8, uu);
    }

    // PV (swapped): O^T[d][q] += V^T[d][k] * P[k][q]
    __builtin_amdgcn_s_setprio(1);
#pragma unroll
    for (int mt = 0; mt < 2; mt++)
#pragma unroll
      for (int ks = 0; ks < 2; ks++) {
        bf16x8 vf = *reinterpret_cast<const bf16x8*>(&Vd[cur][swz64((mt * 32 + q31) * 64 + kh * 32 + ks * 16 + hl * 8)]);
        oacc[mt] = __builtin_amdgcn_mfma_f32_32x32x16_bf16(vf, pb[ks], oacc[mt], 0, 0, 0);
      }
    __builtin_amdgcn_s_setprio(0);
  }

  // per-wave row sum for column q31
  lsum += __shfl_xor(lsum, 32);

  __syncthreads();   // nt may be odd: all waves done reading buf0 before Oc alias write

  // combine key-half partials: kh=1 writes O^T and l, kh=0 finishes
  float* Oc = qg ? (float*)&Vd[0][0] : (float*)&Kd[0][0];   // [64 d][32 q]
  if (kh == 1) {
#pragma unroll
    for (int mt = 0; mt < 2; mt++)
#pragma unroll
      for (int e = 0; e < 16; e++) {
        int d = mt * 32 + (e & 3) + (e >> 2) * 8 + hl * 4;
        Oc[d * 32 + q31] = oacc[mt][e];
      }
    if (hl == 0) Lc[qg][q31] = lsum;
  }
  __syncthreads();
  if (kh == 0) {
    float linv = 1.0f / (lsum + Lc[qg][q31]);
    uint16_t* Xr = X + ((size_t)b * S_LEN + q0 + q31) * EMB + hd * HDIM;
#pragma unroll
    for (int mt = 0; mt < 2; mt++)
#pragma unroll
      for (int s2 = 0; s2 < 4; s2++) {
        int d0 = mt * 32 + s2 * 8 + hl * 4;
        float v0 = (oacc[mt][4 * s2 + 0] + Oc[(d0 + 0) * 32 + q31]) * linv;
        float v1 = (oacc[mt][4 * s2 + 1] + Oc[(d0 + 1) * 32 + q31]) * linv;
        float v2 = (oacc[mt][4 * s2 + 2] + Oc[(d0 + 2) * 32 + q31]) * linv;
        float v3 = (oacc[mt][4 * s2 + 3] + Oc[(d0 + 3) * 32 + q31]) * linv;
        uint2 ww;
        ww.x = cvtpk_bf16(v0, v1);
        ww.y = cvtpk_bf16(v2, v3);
        *reinterpret_cast<uint2*>(Xr + d0) = ww;
      }
  }
}

// ---------------- Proj GEMM (verified r12 body): 64x64 tiles, 768 blocks ----------------
// NEW: bn-fast XCD-chunked decode (96 = 8 bm x 12 bn per XCD): working set
// 0.79MB A-chunk + 1.2MB W = 2MB, fits the XCD's 4MB L2.
__global__ __launch_bounds__(256) void proj_gemm(const uint16_t* __restrict__ A,
                                                 const uint16_t* __restrict__ W,
                                                 const float* __restrict__ bias,
                                                 float* __restrict__ out) {
  __shared__ __align__(16) uint16_t As[64 * 64];
  __shared__ __align__(16) uint16_t Bs[64 * 64];
  const int t    = threadIdx.x;
  const int lane = t & 63;
  const int wv   = t >> 6;
  const int wr   = wv >> 1, wc = wv & 1;
  // bijective XCD swizzle, bn-fast: 768 = 8 * 96, 96 = 8 bm * 12 bn
  const int wg   = (blockIdx.x & 7) * 96 + (blockIdx.x >> 3);
  const int bm   = wg / 12;                  // 64 M tiles; 8 per XCD
  const int bn   = wg % 12;                  // 12 N tiles; all per XCD

  const uint16_t* Ag = A + (size_t)bm * 64 * 768;
  const uint16_t* Wg = W + (size_t)bn * 64 * 768;

  f32x4 zf = {0.f, 0.f, 0.f, 0.f};
  f32x4 acc[2][2];
#pragma unroll
  for (int m = 0; m < 2; m++)
#pragma unroll
    for (int n = 0; n < 2; n++) acc[m][n] = zf;

  for (int k0 = 0; k0 < 768; k0 += 64) {
#pragma unroll
    for (int j = 0; j < 2; j++) {
      int p = j * 256 + t;                   // chunk 0..511
      int r = p >> 3, x = p & 7;
      int scol = (x ^ (r & 7)) << 3;
      gload16(&As[p * 8], Ag + (size_t)r * 768 + k0 + scol);
      gload16(&Bs[p * 8], Wg + (size_t)r * 768 + k0 + scol);
    }
    __syncthreads();
#pragma unroll
    for (int kk = 0; kk < 2; kk++) {
      const int kc = kk * 32 + (lane >> 4) * 8;
      bf16x8 af[2], bf[2];
#pragma unroll
      for (int m = 0; m < 2; m++)
        af[m] = *reinterpret_cast<const bf16x8*>(&As[swz64((wr * 32 + m * 16 + (lane & 15)) * 64 + kc)]);
#pragma unroll
      for (int n = 0; n < 2; n++)
        bf[n] = *reinterpret_cast<const bf16x8*>(&Bs[swz64((wc * 32 + n * 16 + (lane & 15)) * 64 + kc)]);
#pragma unroll
      for (int m = 0; m < 2; m++)
#pragma unroll
        for (int n = 0; n < 2; n++)
          acc[m][n] = __builtin_amdgcn_mfma_f32_16x16x32_bf16(af[m], bf[n], acc[m][n], 0, 0, 0);
    }
    __syncthreads();
  }

#pragma unroll
  for (int n = 0; n < 2; n++) {
    const int f = bn * 64 + wc * 32 + n * 16 + (lane & 15);
    const float bv = bias[f];
#pragma unroll
    for (int m = 0; m < 2; m++)
#pragma unroll
      for (int r = 0; r < 4; r++) {
        int i = bm * 64 + wr * 32 + m * 16 + (lane >> 4) * 4 + r;
        out[(size_t)i * 768 + f] = acc[m][n][r] + bv;
      }
  }
}

extern "C" void kernel_launch(void* const* d_in, const int* in_sizes, int n_in,
                              void* d_out, int out_size, void* d_ws, size_t ws_size,
                              hipStream_t stream) {
  const float* inputs = (const float*)d_in[0];
  const int*   mask   = (const int*)d_in[1];
  const float* w_qkv  = (const float*)d_in[2];
  const float* b_qkv  = (const float*)d_in[3];
  const float* w_proj = (const float*)d_in[4];
  const float* b_proj = (const float*)d_in[5];
  float* out = (float*)d_out;

  uint16_t* a_bf  = (uint16_t*)d_ws;                    // 4096*768
  uint16_t* wq_bf = a_bf  + (size_t)4096 * 768;         // 2304*768
  uint16_t* wp_bf = wq_bf + (size_t)2304 * 768;         // 768*768
  uint16_t* q_bf  = wp_bf + (size_t)768 * 768;          // 24*2048*64
  uint16_t* k_bf  = q_bf  + (size_t)24 * 2048 * 64;     // compacted keys
  uint16_t* v_bf  = k_bf  + (size_t)24 * 2048 * 64;     // compacted, [B,H,D,Sc]
  uint16_t* x_bf  = v_bf  + (size_t)24 * 2048 * 64;     // 4096*768
  int*      cpos  = (int*)(x_bf + (size_t)4096 * 768);  // 2*2048 ints
  float*    mbc   = (float*)(cpos + 2 * 2048);          // 2*2048 floats
  int*      ntp   = (int*)(mbc + 2 * 2048);             // 2 ints
  int*      nbp   = ntp + 2;                            // 2 ints

  const int n0 = 4096 * 768 / 4, n1 = 2304 * 768 / 4, n2 = 768 * 768 / 4;
  cvt_all<<<(n0 + n1 + n2 + 255) / 256, 256, 0, stream>>>(
      (const float4*)inputs, (ushort4*)a_bf, n0,
      (const float4*)w_qkv,  (ushort4*)wq_bf, n1,
      (const float4*)w_proj, (ushort4*)wp_bf, n2);
  mask_scan<<<2, 256, 0, stream>>>(mask, cpos, mbc, ntp, nbp);
  pad_fill<<<2 * NHEAD, 256, 0, stream>>>(nbp, k_bf, v_bf);
  qkv_gemm<<<32 * 36, 256, 0, stream>>>(a_bf, wq_bf, b_qkv, cpos, q_bf, k_bf, v_bf);
  attn_kernel<<<24 * 32, 256, 0, stream>>>(q_bf, k_bf, v_bf, mbc, ntp, x_bf);
  proj_gemm<<<64 * 12, 256, 0, stream>>>(x_bf, wp_bf, b_proj, out);
}

// Round 18
// 82.399 us; speedup vs baseline: 1.4225x; 1.0087x over previous
//
#include <hip/hip_runtime.h>
#include <stdint.h>

#define S_LEN 2048
#define EMB   768
#define NHEAD 12
#define HDIM  64

typedef __attribute__((ext_vector_type(8)))  __bf16       bf16x8;
typedef __attribute__((ext_vector_type(4)))  float        f32x4;
typedef __attribute__((ext_vector_type(16))) float        f32x16;
typedef __attribute__((ext_vector_type(2)))  unsigned int u32x2;
typedef __attribute__((ext_vector_type(4)))  unsigned int u32x4;

__device__ __forceinline__ uint16_t f32_to_bf16(float f) {
  uint32_t u = __float_as_uint(f);
  u += 0x7FFFu + ((u >> 16) & 1u);           // round-to-nearest-even
  return (uint16_t)(u >> 16);
}

__device__ __forceinline__ uint32_t cvtpk_bf16(float lo, float hi) {
  uint32_t r;
  asm("v_cvt_pk_bf16_f32 %0, %1, %2" : "=v"(r) : "v"(lo), "v"(hi));
  return r;
}

#if __has_builtin(__builtin_amdgcn_exp2f)
#define EXP2F(x) __builtin_amdgcn_exp2f(x)
#else
#define EXP2F(x) exp2f(x)
#endif

#define ZERO16 {0.f,0.f,0.f,0.f,0.f,0.f,0.f,0.f,0.f,0.f,0.f,0.f,0.f,0.f,0.f,0.f}

// XOR swizzle for [rows][64] bf16 LDS tiles (idx in ushort units).
__device__ __forceinline__ int swz64(int idx) {
  return idx ^ (((idx >> 6) & 7) << 3);
}

// XOR swizzle for [rows][128] bf16 LDS tiles (idx in ushort units):
// flips idx bits 3..5 (16B-chunk low bits) with row&7. Involution.
__device__ __forceinline__ int swz128(int idx) {
  return idx ^ (((idx >> 7) & 7) << 3);
}

// async global->LDS, 16B per lane; dest must be linear (wave base + lane*16)
__device__ __forceinline__ void gload16(uint16_t* lds, const uint16_t* g) {
  __builtin_amdgcn_global_load_lds((const __attribute__((address_space(1))) void*)g,
                                   (__attribute__((address_space(3))) void*)lds, 16, 0, 0);
}

// ---------------- fused fp32 -> bf16 convert (verified r12) ----------------
__global__ __launch_bounds__(256) void cvt_all(const float4* __restrict__ i0, ushort4* __restrict__ o0, int n0,
                                               const float4* __restrict__ i1, ushort4* __restrict__ o1, int n1,
                                               const float4* __restrict__ i2, ushort4* __restrict__ o2, int n2) {
  int gid = blockIdx.x * blockDim.x + threadIdx.x;
  const float4* src;
  ushort4* dst;
  int idx;
  if (gid < n0)           { src = i0; dst = o0; idx = gid; }
  else if (gid < n0 + n1) { src = i1; dst = o1; idx = gid - n0; }
  else if (gid < n0 + n1 + n2) { src = i2; dst = o2; idx = gid - n0 - n1; }
  else return;
  float4 v = src[idx];
  ushort4 o;
  o.x = f32_to_bf16(v.x); o.y = f32_to_bf16(v.y);
  o.z = f32_to_bf16(v.z); o.w = f32_to_bf16(v.w);
  dst[idx] = o;
}

// ---------------- mask scan (parallel): cpos, compact bias, tile counts ----------------
__global__ __launch_bounds__(256) void mask_scan(const int* __restrict__ mask,
                                                 int* __restrict__ cpos,
                                                 float* __restrict__ mbc,
                                                 int* __restrict__ ntp,
                                                 int* __restrict__ nbp) {
  const int b    = blockIdx.x;
  const int t    = threadIdx.x;
  const int lane = t & 63;
  const int wvi  = t >> 6;
  __shared__ int wsum[4];
  int m[8], u = 0;
#pragma unroll
  for (int j = 0; j < 8; j++) {
    m[j] = mask[b * S_LEN + t * 8 + j];
    u += (m[j] == 0);
  }
  // wave-level inclusive scan of u
  int x = u;
#pragma unroll
  for (int off = 1; off < 64; off <<= 1) {
    int v = __shfl_up(x, off);
    if (lane >= off) x += v;
  }
  if (lane == 63) wsum[wvi] = x;
  __syncthreads();
  int wbase = 0;
#pragma unroll
  for (int i = 0; i < 4; i++) wbase += (i < wvi) ? wsum[i] : 0;
  const int nb = wsum[0] + wsum[1] + wsum[2] + wsum[3];
  int base = wbase + x - u;                 // exclusive prefix for this thread
#pragma unroll
  for (int j = 0; j < 8; j++) {
    int sc = (m[j] == 0) ? base : -1;
    if (m[j] == 0) base++;
    cpos[b * S_LEN + t * 8 + j] = sc;
    mbc[b * S_LEN + t * 8 + j] = ((t * 8 + j) < nb) ? 0.0f : -1e30f;
  }
  if (t == 0) {
    ntp[b] = ((nb + 63) & ~63) >> 6;
    nbp[b] = nb;
  }
}

// ---------------- pad fill: zero the <=63 pad rows of K / pad cols of V^T ----------------
__global__ __launch_bounds__(256) void pad_fill(const int* __restrict__ nbp,
                                                uint16_t* __restrict__ kb,
                                                uint16_t* __restrict__ vb) {
  const int b = blockIdx.x / NHEAD, h = blockIdx.x % NHEAD;
  const int t = threadIdx.x;
  const int nb = nbp[b];
  const int padN = (nb + 63) & ~63;
  const int npad = padN - nb;
  for (int idx = t; idx < npad * HDIM; idx += 256) {
    int row = idx >> 6, d = idx & (HDIM - 1);
    kb[(((size_t)b * NHEAD + h) * S_LEN + nb + row) * HDIM + d] = 0;
    vb[(((size_t)b * NHEAD + h) * HDIM + d) * S_LEN + nb + row] = 0;
  }
}

// ---------------- QKV GEMM: BM=128, BN=64, BK=128 (6 K-iters), 1152 blocks ----------------
// BK 64->128 halves the per-iteration fixed cost (~1000cy barrier/drain) that the
// iter-cost model (attn/qkv/m97 calibration: ~1000cy + ~15cy/KB) says dominates.
// LDS 48KB single-buffer -> still 3 blocks/CU. swz128 swizzle (verified bank math).
__global__ __launch_bounds__(256) void qkv_gemm(const uint16_t* __restrict__ A,
                                                const uint16_t* __restrict__ W,
                                                const float* __restrict__ bias,
                                                const int* __restrict__ cpos,
                                                uint16_t* __restrict__ qb,
                                                uint16_t* __restrict__ kb,
                                                uint16_t* __restrict__ vb) {
  __shared__ __align__(16) uint16_t As[128 * 128];   // 32KB
  __shared__ __align__(16) uint16_t Bs[64 * 128];    // 16KB
  const int t    = threadIdx.x;
  const int lane = t & 63;
  const int wv   = t >> 6;
  const int wr   = wv >> 1, wc = wv & 1;
  // bijective XCD swizzle, bn-fast: 1152 = 8 * 144, 144 = 4 bm * 36 bn
  const int wg   = (blockIdx.x & 7) * 144 + (blockIdx.x >> 3);
  const int bm   = wg / 36;                  // 32 M tiles (128 rows); 4 per XCD
  const int bn   = wg % 36;                  // 36 N tiles (64 cols); all per XCD

  const uint16_t* Ag = A + (size_t)bm * 128 * 768;
  const uint16_t* Wg = W + (size_t)bn * 64 * 768;

  f32x4 zf = {0.f, 0.f, 0.f, 0.f};
  f32x4 acc[4][2];
#pragma unroll
  for (int m = 0; m < 4; m++)
#pragma unroll
    for (int n = 0; n < 2; n++) acc[m][n] = zf;

  for (int k0 = 0; k0 < 768; k0 += 128) {
    // A tile: 128 rows x 16 chunks = 2048 chunks, 8 per thread
#pragma unroll
    for (int j = 0; j < 8; j++) {
      int p = j * 256 + t;
      int r = p >> 4, x = p & 15;
      int scol = (((x & 8) | ((x & 7) ^ (r & 7)))) << 3;   // inverse-swizzled source chunk
      gload16(&As[p * 8], Ag + (size_t)r * 768 + k0 + scol);
    }
    // B tile: 64 rows x 16 chunks = 1024 chunks, 4 per thread
#pragma unroll
    for (int j = 0; j < 4; j++) {
      int p = j * 256 + t;
      int r = p >> 4, x = p & 15;
      int scol = (((x & 8) | ((x & 7) ^ (r & 7)))) << 3;
      gload16(&Bs[p * 8], Wg + (size_t)r * 768 + k0 + scol);
    }
    __syncthreads();
#pragma unroll
    for (int kk = 0; kk < 4; kk++) {
      const int kc = kk * 32 + (lane >> 4) * 8;
      bf16x8 af[4], bf[2];
#pragma unroll
      for (int m = 0; m < 4; m++)
        af[m] = *reinterpret_cast<const bf16x8*>(&As[swz128((wr * 64 + m * 16 + (lane & 15)) * 128 + kc)]);
#pragma unroll
      for (int n = 0; n < 2; n++)
        bf[n] = *reinterpret_cast<const bf16x8*>(&Bs[swz128((wc * 32 + n * 16 + (lane & 15)) * 128 + kc)]);
#pragma unroll
      for (int m = 0; m < 4; m++)
#pragma unroll
        for (int n = 0; n < 2; n++)
          acc[m][n] = __builtin_amdgcn_mfma_f32_16x16x32_bf16(af[m], bf[n], acc[m][n], 0, 0, 0);
    }
    __syncthreads();
  }

  const int cQ = bn / 12;                    // 0=Q, 1=K, 2=V (block-uniform)
  int scv[4][4];
  if (cQ != 0) {
#pragma unroll
    for (int m = 0; m < 4; m++)
#pragma unroll
      for (int r = 0; r < 4; r++) {
        int i = bm * 128 + wr * 64 + m * 16 + (lane >> 4) * 4 + r;
        scv[m][r] = cpos[(i >> 11) * S_LEN + (i & 2047)];
      }
  }
#pragma unroll
  for (int n = 0; n < 2; n++) {
    const int f   = bn * 64 + wc * 32 + n * 16 + (lane & 15);
    const float bv = bias[f];
    const int rem = f - cQ * 768;
    const int h   = rem >> 6, d = rem & 63;
    const float scl = (cQ == 0) ? 0.125f * 1.44269504f : 1.0f;  // SCALE*log2e folded into Q
#pragma unroll
    for (int m = 0; m < 4; m++) {
#pragma unroll
      for (int r = 0; r < 4; r++) {
        int i = bm * 128 + wr * 64 + m * 16 + (lane >> 4) * 4 + r;
        int b = i >> 11, s = i & 2047;
        uint16_t val = f32_to_bf16((acc[m][n][r] + bv) * scl);
        if (cQ == 0) {
          qb[(((size_t)b * NHEAD + h) * S_LEN + s) * HDIM + d] = val;
        } else {
          int sc = scv[m][r];
          if (sc >= 0) {
            if (cQ == 1)
              kb[(((size_t)b * NHEAD + h) * S_LEN + sc) * HDIM + d] = val;
            else
              vb[(((size_t)b * NHEAD + h) * HDIM + d) * S_LEN + sc] = val;  // V transposed
          }
        }
      }
    }
  }
}

// ---------------- Flash attention (verified r16): compacted keys, tail-only bias ----------------
__global__ __launch_bounds__(256, 3) void attn_kernel(const uint16_t* __restrict__ Q,   // [BH][S][D], pre-scaled
                                                      const uint16_t* __restrict__ Kb,  // [BH][Sc][D] compacted
                                                      const uint16_t* __restrict__ Vb,  // [BH][D][Sc] compacted
                                                      const float* __restrict__ mbc,    // [B][S] compact bias
                                                      const int* __restrict__ ntp,      // [B] tile count
                                                      uint16_t* __restrict__ X) {       // [B][S][E] bf16
  __shared__ __align__(16) uint16_t Kd[2][64 * 64];
  __shared__ __align__(16) uint16_t Vd[2][64 * 64];   // [d][key]
  __shared__ __align__(16) float    mb_s[S_LEN];
  __shared__ float Lc[2][32];

  const int t    = threadIdx.x;
  const int lane = t & 63;
  const int hl   = lane >> 5;                   // lane half
  const int q31  = lane & 31;
  const int wv   = t >> 6;
  const int qg   = wv & 1;                      // q-group
  const int kh   = wv >> 1;                     // key-half
  // bijective XCD swizzle: 768 = 8 * 96; each XCD gets 3 whole heads (L2-fit K/V)
  const int wg   = (blockIdx.x & 7) * 96 + (blockIdx.x >> 3);
  const int qblk = wg & 31;
  const int bh   = wg >> 5;
  const int b    = bh / NHEAD, hd = bh % NHEAD;

  const uint16_t* Qh = Q  + (size_t)bh * S_LEN * HDIM;
  const uint16_t* Kh = Kb + (size_t)bh * S_LEN * HDIM;
  const uint16_t* Vh = Vb + (size_t)bh * HDIM * S_LEN;
  const int q0 = qblk * 64 + qg * 32;
  const int nt = ntp[b];

  // compact bias preload (8 keys/thread, coalesced float4)
  {
    float4 f0 = *reinterpret_cast<const float4*>(&mbc[b * S_LEN + t * 8]);
    float4 f1 = *reinterpret_cast<const float4*>(&mbc[b * S_LEN + t * 8 + 4]);
    *reinterpret_cast<float4*>(&mb_s[t * 8])     = f0;
    *reinterpret_cast<float4*>(&mb_s[t * 8 + 4]) = f1;
  }

  // Q as B-fragments: col=q31, k=d=16s+8hl+j
  bf16x8 qf[4];
#pragma unroll
  for (int s = 0; s < 4; s++)
    qf[s] = *reinterpret_cast<const bf16x8*>(Qh + (size_t)(q0 + q31) * HDIM + 16 * s + 8 * hl);

  f32x16 oacc[2] = {ZERO16, ZERO16};
  float lsum = 0.f;

  const uint16_t* kga[2]; const uint16_t* vga[2]; int lof[2];
#pragma unroll
  for (int j = 0; j < 2; j++) {
    int p = j * 256 + t, r = p >> 3, x = p & 7;
    int scol = (x ^ (r & 7)) << 3;
    kga[j] = Kh + (size_t)r * HDIM + scol;
    vga[j] = Vh + (size_t)r * S_LEN + scol;
    lof[j] = p * 8;
  }
  auto stage = [&](int nb2, int it2) {   // 4 vmem instructions per thread
#pragma unroll
    for (int j = 0; j < 2; j++) {
      gload16(&Kd[nb2][lof[j]], kga[j] + it2 * 64 * HDIM);
      gload16(&Vd[nb2][lof[j]], vga[j] + it2 * 64);
    }
  };

  stage(0, 0);
  __syncthreads();                       // prologue: full drain, bias + buf0 ready

#pragma unroll 2
  for (int it = 0; it < nt; ++it) {
    const int cur = it & 1;
    __builtin_amdgcn_s_barrier();        // A: all waves done compute(it-1) -> buf cur^1 free
    __builtin_amdgcn_sched_barrier(0);
    if (it + 1 < nt) {
      stage(cur ^ 1, it + 1);            // next-tile loads: stay in flight across B
      asm volatile("s_waitcnt vmcnt(4)" ::: "memory");   // my tile-it loads done
    } else {
      asm volatile("s_waitcnt vmcnt(0)" ::: "memory");
    }
    __builtin_amdgcn_s_barrier();        // B: buf cur staged block-wide
    __builtin_amdgcn_sched_barrier(0);

    // QK^T (swapped): scc[reg] = S[key_loc=(reg&3)+8*(reg>>2)+4*hl][q31]
    f32x16 scc = ZERO16;
    __builtin_amdgcn_s_setprio(1);
#pragma unroll
    for (int s = 0; s < 4; s++) {
      bf16x8 kf = *reinterpret_cast<const bf16x8*>(&Kd[cur][swz64((kh * 32 + q31) * 64 + 16 * s + 8 * hl)]);
      scc = __builtin_amdgcn_mfma_f32_32x32x16_bf16(kf, qf[s], scc, 0, 0, 0);
    }
    __builtin_amdgcn_s_setprio(0);

    // exp2 + per-lane sum; bias only on the tail tile (compacted keys have bias 0)
    uint32_t w[4][2];
    if (it == nt - 1) {
#pragma unroll
      for (int s2 = 0; s2 < 4; s2++) {
        f32x4 mbv = *reinterpret_cast<const f32x4*>(&mb_s[it * 64 + kh * 32 + s2 * 8 + hl * 4]);
        float p0 = EXP2F(scc[4 * s2 + 0] + mbv[0]);
        float p1 = EXP2F(scc[4 * s2 + 1] + mbv[1]);
        float p2 = EXP2F(scc[4 * s2 + 2] + mbv[2]);
        float p3 = EXP2F(scc[4 * s2 + 3] + mbv[3]);
        lsum += (p0 + p1) + (p2 + p3);
        w[s2][0] = cvtpk_bf16(p0, p1);
        w[s2][1] = cvtpk_bf16(p2, p3);
      }
    } else {
#pragma unroll
      for (int s2 = 0; s2 < 4; s2++) {
        float p0 = EXP2F(scc[4 * s2 + 0]);
        float p1 = EXP2F(scc[4 * s2 + 1]);
        float p2 = EXP2F(scc[4 * s2 + 2]);
        float p3 = EXP2F(scc[4 * s2 + 3]);
        lsum += (p0 + p1) + (p2 + p3);
        w[s2][0] = cvtpk_bf16(p0, p1);
        w[s2][1] = cvtpk_bf16(p2, p3);
      }
    }

    // redistribute P into PV B-fragments: pb[ks][j] = P[16ks+8hl+j][q31]
    bf16x8 pb[2];
#pragma unroll
    for (int ks = 0; ks < 2; ks++) {
      u32x2 r0 = __builtin_amdgcn_permlane32_swap(w[2 * ks][0], w[2 * ks + 1][0], false, false);
      u32x2 r1 = __builtin_amdgcn_permlane32_swap(w[2 * ks][1], w[2 * ks + 1][1], false, false);
      u32x4 uu;
      uu.x = r0.x; uu.y = r1.x; uu.z = r0.y; uu.w = r1.y;
      pb[ks] = __builtin_bit_cast(bf16x8, uu);
    }

    // PV (swapped): O^T[d][q] += V^T[d][k] * P[k][q]
    __builtin_amdgcn_s_setprio(1);
#pragma unroll
    for (int mt = 0; mt < 2; mt++)
#pragma unroll
      for (int ks = 0; ks < 2; ks++) {
        bf16x8 vf = *reinterpret_cast<const bf16x8*>(&Vd[cur][swz64((mt * 32 + q31) * 64 + kh * 32 + ks * 16 + hl * 8)]);
        oacc[mt] = __builtin_amdgcn_mfma_f32_32x32x16_bf16(vf, pb[ks], oacc[mt], 0, 0, 0);
      }
    __builtin_amdgcn_s_setprio(0);
  }

  // per-wave row sum for column q31
  lsum += __shfl_xor(lsum, 32);

  __syncthreads();   // nt may be odd: all waves done reading buf0 before Oc alias write

  // combine key-half partials: kh=1 writes O^T and l, kh=0 finishes
  float* Oc = qg ? (float*)&Vd[0][0] : (float*)&Kd[0][0];   // [64 d][32 q]
  if (kh == 1) {
#pragma unroll
    for (int mt = 0; mt < 2; mt++)
#pragma unroll
      for (int e = 0; e < 16; e++) {
        int d = mt * 32 + (e & 3) + (e >> 2) * 8 + hl * 4;
        Oc[d * 32 + q31] = oacc[mt][e];
      }
    if (hl == 0) Lc[qg][q31] = lsum;
  }
  __syncthreads();
  if (kh == 0) {
    float linv = 1.0f / (lsum + Lc[qg][q31]);
    uint16_t* Xr = X + ((size_t)b * S_LEN + q0 + q31) * EMB + hd * HDIM;
#pragma unroll
    for (int mt = 0; mt < 2; mt++)
#pragma unroll
      for (int s2 = 0; s2 < 4; s2++) {
        int d0 = mt * 32 + s2 * 8 + hl * 4;
        float v0 = (oacc[mt][4 * s2 + 0] + Oc[(d0 + 0) * 32 + q31]) * linv;
        float v1 = (oacc[mt][4 * s2 + 1] + Oc[(d0 + 1) * 32 + q31]) * linv;
        float v2 = (oacc[mt][4 * s2 + 2] + Oc[(d0 + 2) * 32 + q31]) * linv;
        float v3 = (oacc[mt][4 * s2 + 3] + Oc[(d0 + 3) * 32 + q31]) * linv;
        uint2 ww;
        ww.x = cvtpk_bf16(v0, v1);
        ww.y = cvtpk_bf16(v2, v3);
        *reinterpret_cast<uint2*>(Xr + d0) = ww;
      }
  }
}

// ---------------- Proj GEMM (verified r17): 64x64 tiles, bn-fast XCD decode ----------------
__global__ __launch_bounds__(256) void proj_gemm(const uint16_t* __restrict__ A,
                                                 const uint16_t* __restrict__ W,
                                                 const float* __restrict__ bias,
                                                 float* __restrict__ out) {
  __shared__ __align__(16) uint16_t As[64 * 64];
  __shared__ __align__(16) uint16_t Bs[64 * 64];
  const int t    = threadIdx.x;
  const int lane = t & 63;
  const int wv   = t >> 6;
  const int wr   = wv >> 1, wc = wv & 1;
  // bijective XCD swizzle, bn-fast: 768 = 8 * 96, 96 = 8 bm * 12 bn
  const int wg   = (blockIdx.x & 7) * 96 + (blockIdx.x >> 3);
  const int bm   = wg / 12;                  // 64 M tiles; 8 per XCD
  const int bn   = wg % 12;                  // 12 N tiles; all per XCD

  const uint16_t* Ag = A + (size_t)bm * 64 * 768;
  const uint16_t* Wg = W + (size_t)bn * 64 * 768;

  f32x4 zf = {0.f, 0.f, 0.f, 0.f};
  f32x4 acc[2][2];
#pragma unroll
  for (int m = 0; m < 2; m++)
#pragma unroll
    for (int n = 0; n < 2; n++) acc[m][n] = zf;

  for (int k0 = 0; k0 < 768; k0 += 64) {
#pragma unroll
    for (int j = 0; j < 2; j++) {
      int p = j * 256 + t;                   // chunk 0..511
      int r = p >> 3, x = p & 7;
      int scol = (x ^ (r & 7)) << 3;
      gload16(&As[p * 8], Ag + (size_t)r * 768 + k0 + scol);
      gload16(&Bs[p * 8], Wg + (size_t)r * 768 + k0 + scol);
    }
    __syncthreads();
#pragma unroll
    for (int kk = 0; kk < 2; kk++) {
      const int kc = kk * 32 + (lane >> 4) * 8;
      bf16x8 af[2], bf[2];
#pragma unroll
      for (int m = 0; m < 2; m++)
        af[m] = *reinterpret_cast<const bf16x8*>(&As[swz64((wr * 32 + m * 16 + (lane & 15)) * 64 + kc)]);
#pragma unroll
      for (int n = 0; n < 2; n++)
        bf[n] = *reinterpret_cast<const bf16x8*>(&Bs[swz64((wc * 32 + n * 16 + (lane & 15)) * 64 + kc)]);
#pragma unroll
      for (int m = 0; m < 2; m++)
#pragma unroll
        for (int n = 0; n < 2; n++)
          acc[m][n] = __builtin_amdgcn_mfma_f32_16x16x32_bf16(af[m], bf[n], acc[m][n], 0, 0, 0);
    }
    __syncthreads();
  }

#pragma unroll
  for (int n = 0; n < 2; n++) {
    const int f = bn * 64 + wc * 32 + n * 16 + (lane & 15);
    const float bv = bias[f];
#pragma unroll
    for (int m = 0; m < 2; m++)
#pragma unroll
      for (int r = 0; r < 4; r++) {
        int i = bm * 64 + wr * 32 + m * 16 + (lane >> 4) * 4 + r;
        out[(size_t)i * 768 + f] = acc[m][n][r] + bv;
      }
  }
}

extern "C" void kernel_launch(void* const* d_in, const int* in_sizes, int n_in,
                              void* d_out, int out_size, void* d_ws, size_t ws_size,
                              hipStream_t stream) {
  const float* inputs = (const float*)d_in[0];
  const int*   mask   = (const int*)d_in[1];
  const float* w_qkv  = (const float*)d_in[2];
  const float* b_qkv  = (const float*)d_in[3];
  const float* w_proj = (const float*)d_in[4];
  const float* b_proj = (const float*)d_in[5];
  float* out = (float*)d_out;

  uint16_t* a_bf  = (uint16_t*)d_ws;                    // 4096*768
  uint16_t* wq_bf = a_bf  + (size_t)4096 * 768;         // 2304*768
  uint16_t* wp_bf = wq_bf + (size_t)2304 * 768;         // 768*768
  uint16_t* q_bf  = wp_bf + (size_t)768 * 768;          // 24*2048*64
  uint16_t* k_bf  = q_bf  + (size_t)24 * 2048 * 64;     // compacted keys
  uint16_t* v_bf  = k_bf  + (size_t)24 * 2048 * 64;     // compacted, [B,H,D,Sc]
  uint16_t* x_bf  = v_bf  + (size_t)24 * 2048 * 64;     // 4096*768
  int*      cpos  = (int*)(x_bf + (size_t)4096 * 768);  // 2*2048 ints
  float*    mbc   = (float*)(cpos + 2 * 2048);          // 2*2048 floats
  int*      ntp   = (int*)(mbc + 2 * 2048);             // 2 ints
  int*      nbp   = ntp + 2;                            // 2 ints

  const int n0 = 4096 * 768 / 4, n1 = 2304 * 768 / 4, n2 = 768 * 768 / 4;
  cvt_all<<<(n0 + n1 + n2 + 255) / 256, 256, 0, stream>>>(
      (const float4*)inputs, (ushort4*)a_bf, n0,
      (const float4*)w_qkv,  (ushort4*)wq_bf, n1,
      (const float4*)w_proj, (ushort4*)wp_bf, n2);
  mask_scan<<<2, 256, 0, stream>>>(mask, cpos, mbc, ntp, nbp);
  pad_fill<<<2 * NHEAD, 256, 0, stream>>>(nbp, k_bf, v_bf);
  qkv_gemm<<<32 * 36, 256, 0, stream>>>(a_bf, wq_bf, b_qkv, cpos, q_bf, k_bf, v_bf);
  attn_kernel<<<24 * 32, 256, 0, stream>>>(q_bf, k_bf, v_bf, mbc, ntp, x_bf);
  proj_gemm<<<64 * 12, 256, 0, stream>>>(x_bf, wp_bf, b_proj, out);
}